// Round 14
// baseline (2089.428 us; speedup 1.0000x reference)
//
#include <hip/hip_runtime.h>
#include <stdint.h>
#include <math.h>

// ============================================================================
// RPN forward (detectron2-style) on MI355X — fp64 ordering-exact pipeline.
// R14: NMS greedy scan chain de-shfl'd — per 64-row group the diagonal block
// is loaded into REGISTERS (d[64], fully unrolled static indices) in every
// lane; the serial resolve is pure VALU (~10 cyc/step vs ~250ns/step for the
// dependent-shfl chain that cost 533us). k_post now 256 threads (1024-thread
// blocks cap VGPR at 128 and d[64] alone is 128).
// ============================================================================

#define R_TOT   130944
#define HALF_R  65472
#define TOTK    7920
#define SCALE_CLAMP 4.135166556742356  // log(1000/16)

// ---------------- threefry2x32-20 (JAX-compatible) ----------------
__host__ __device__ inline void threefry(uint32_t k0, uint32_t k1,
                                         uint32_t x0, uint32_t x1,
                                         uint32_t* o0, uint32_t* o1)
{
  uint32_t ks[3]; ks[0]=k0; ks[1]=k1; ks[2]=k0^k1^0x1BD11BDAu;
  x0 += ks[0]; x1 += ks[1];
  const uint32_t rot0[4] = {13u,15u,26u,6u};
  const uint32_t rot1[4] = {17u,29u,16u,24u};
  for (int i = 0; i < 5; i++){
    const uint32_t* rot = (i & 1) ? rot1 : rot0;
    for (int q = 0; q < 4; q++){
      x0 += x1;
      x1 = (x1 << rot[q]) | (x1 >> (32u - rot[q]));
      x1 ^= x0;
    }
    x0 += ks[(i+1)%3];
    x1 += ks[(i+2)%3] + (uint32_t)(i+1);
  }
  *o0 = x0; *o1 = x1;
}

// ---------------- helpers ----------------
__device__ inline unsigned long long mono64(double v){
  unsigned long long b = (unsigned long long)__double_as_longlong(v);
  return (b & 0x8000000000000000ull) ? ~b : (b | 0x8000000000000000ull);
}

__device__ __forceinline__ double iou_cf(double g0,double g1,double g2,double g3,
                                         double a0,double a1,double a2,double a3){
  #pragma clang fp contract(off)
  double lt0 = fmax(g0,a0), lt1 = fmax(g1,a1);
  double rb0 = fmin(g2,a2), rb1 = fmin(g3,a3);
  double w = rb0-lt0; if (w<0.0) w=0.0;
  double h = rb1-lt1; if (h<0.0) h=0.0;
  double inter = w*h;
  double aa = (g2-g0)*(g3-g1);
  double ab = (a2-a0)*(a3-a1);
  double uni = aa+ab-inter;
  return inter>0.0 ? inter/uni : 0.0;
}

__device__ __forceinline__ void anchor_of(int r, double* o){
  #pragma clang fp contract(off)
  const int    base[5]={0,98304,122880,129024,130560};
  const int    Wl[5]  ={256,128,64,32,16};
  const double strd[5]={4.0,8.0,16.0,32.0,64.0};
  const double size[5]={32.0,64.0,128.0,256.0,512.0};
  const double ratio[3]={0.5,1.0,2.0};
  int l=0; while (l<4 && r>=base[l+1]) l++;
  int rr=r-base[l]; int pix=rr/3; int a=rr-pix*3;
  int x=pix%Wl[l], y=pix/Wl[l];
  double w=sqrt(size[l]*size[l]/ratio[a]);
  double h=w*ratio[a];
  double sx=(double)x*strd[l], sy=(double)y*strd[l];
  o[0]=sx-0.5*w; o[1]=sy-0.5*h; o[2]=sx+0.5*w; o[3]=sy+0.5*h;
}

// apply_deltas + clip
__device__ __forceinline__ void decode_box(int ridx, const double* __restrict__ d,
                                           double* __restrict__ o){
  double a[4]; anchor_of(ridx,a);
  double w=a[2]-a[0], h=a[3]-a[1];
  double cx=a[0]+0.5*w, cy=a[1]+0.5*h;
  double dw=fmin(d[2],SCALE_CLAMP), dh=fmin(d[3],SCALE_CLAMP);
  double pcx=d[0]*w+cx, pcy=d[1]*h+cy;
  double pw=exp(dw)*w, ph=exp(dh)*h;
  double x1=pcx-0.5*pw, y1=pcy-0.5*ph;
  double x2=pcx+0.5*pw, y2=pcy+0.5*ph;
  o[0]=fmin(fmax(x1,0.0),1024.0); o[1]=fmin(fmax(y1,0.0),512.0);
  o[2]=fmin(fmax(x2,0.0),1024.0); o[3]=fmin(fmax(y2,0.0),512.0);
}

__device__ inline void bitonic_desc(double* sv, int* si, int M, int tid, int nthr){
  for (int k=2;k<=M;k<<=1)
    for (int j=k>>1;j>0;j>>=1){
      __syncthreads();
      for (int i=tid;i<M;i+=nthr){
        int ixj=i^j;
        if (ixj>i){
          double va=sv[i], vb=sv[ixj]; int ia=si[i], ib=si[ixj];
          bool before = (va>vb) || (va==vb && ia<ib);
          bool up = ((i&k)==0);
          if (up ? !before : before){ sv[i]=vb; sv[ixj]=va; si[i]=ib; si[ixj]=ia; }
        }
      }
    }
  __syncthreads();
}

__device__ inline void bitonic_asc_u(uint32_t* sk, int* si, int M, int tid, int nthr){
  for (int k=2;k<=M;k<<=1)
    for (int j=k>>1;j>0;j>>=1){
      __syncthreads();
      for (int i=tid;i<M;i+=nthr){
        int ixj=i^j;
        if (ixj>i){
          uint32_t ka=sk[i], kb=sk[ixj]; int ia=si[i], ib=si[ixj];
          bool before = (ka<kb) || (ka==kb && ia<ib);
          bool up = ((i&k)==0);
          if (up ? !before : before){ sk[i]=kb; sk[ixj]=ka; si[i]=ib; si[ixj]=ia; }
        }
      }
    }
  __syncthreads();
}

// Parallel select over hist[256] (in-place inclusive scan). Works for any
// blockDim >= 256.
__device__ inline void hist_select(int* hist, int kneed, int tid,
                                   int* shb, int* shk){
  for (int off=1; off<256; off<<=1){
    int v=0;
    if (tid<256 && tid>=off) v=hist[tid-off];
    __syncthreads();
    if (tid<256) hist[tid]+=v;
    __syncthreads();
  }
  if (tid<256){
    int prev = tid ? hist[tid-1] : 0;
    if (prev < kneed && kneed <= hist[tid]){ *shb=tid; *shk=kneed-prev; }
    if (tid==255 && kneed > hist[255]){ *shb=255; *shk=kneed-hist[254]; }
  }
  __syncthreads();
}

// ============================================================================
// Kernel A (k_pre): [0,576): weight permute cw->cwTf[ci][k9][cc] f32.
//                   [576,704): per-gt max IoU (gtmax).
// ============================================================================
__global__ __launch_bounds__(256) void k_pre(const float* __restrict__ cw,
    float* __restrict__ cwTf, const float* __restrict__ gt,
    unsigned long long* __restrict__ highest)
{
  const int bx=blockIdx.x, tid=threadIdx.x;
  if (bx < 576){
    int o = bx*256 + tid;
    if (o >= 147456) return;
    int cc = o & 127; int t = o >> 7;
    int k9 = t % 9;  int ci = t / 9;
    cwTf[(size_t)(ci*9+k9)*128 + cc] = cw[(size_t)cc*1152 + ci*9 + k9];
  } else {
    __shared__ double gts[128];
    __shared__ unsigned long long lmax[32];
    const int gb=bx-576;
    const int img=gb>>6, b=gb&63;
    if (tid<128) gts[tid]=(double)gt[img*128+tid];
    if (tid<32) lmax[tid]=0ull;
    __syncthreads();
    double gm[32];
    #pragma unroll
    for (int g=0;g<32;g++) gm[g]=0.0;
    for (int r=b*256+tid; r<R_TOT; r+=64*256){
      double a[4]; anchor_of(r,a);
      #pragma unroll
      for (int g=0;g<32;g++){
        double v=iou_cf(gts[g*4],gts[g*4+1],gts[g*4+2],gts[g*4+3],a[0],a[1],a[2],a[3]);
        gm[g]=fmax(gm[g],v);
      }
    }
    #pragma unroll
    for (int g=0;g<32;g++){
      double v=gm[g];
      #pragma unroll
      for (int off=1; off<64; off<<=1) v=fmax(v,__shfl_xor(v,off));
      if ((tid&63)==0) atomicMax(&lmax[g],(unsigned long long)__double_as_longlong(v));
    }
    __syncthreads();
    if (tid<32) atomicMax(&highest[img*32+tid], lmax[tid]);
  }
}

// ============================================================================
// Kernel B (k_conv_label): [0,2728): conv+heads. [2728,3752): labels.
// [3752,4775): threefry ubits.
// ============================================================================
#define CTH 4
#define CTW 8

__global__ __launch_bounds__(256,3) void k_conv_label(
    const float* __restrict__ f2, const float* __restrict__ f3,
    const float* __restrict__ f4, const float* __restrict__ f5,
    const float* __restrict__ f6,
    const float* __restrict__ cwTf, const float* __restrict__ cb,
    const float* __restrict__ ow, const float* __restrict__ ob,
    const float* __restrict__ dwt, const float* __restrict__ dbt,
    double* __restrict__ logits, double* __restrict__ dpred,
    const float* __restrict__ gt, const unsigned long long* __restrict__ highest,
    int* __restrict__ prelab, int* __restrict__ matched,
    int* __restrict__ labels, int* __restrict__ counts,
    uint32_t* __restrict__ ub,
    uint32_t kf00,uint32_t kf01,uint32_t kb00,uint32_t kb01,
    uint32_t kf10,uint32_t kf11,uint32_t kb10,uint32_t kb11)
{
  __shared__ double fshd[4][6][12];
  __shared__ __align__(16) char ush[18432];   // wshF [4][9][128] f32 / hshp [128][17] dbl / label arrays
  float*  wshF = (float*)ush;
  double* hshp = (double*)ush;
  __shared__ float hw[15*128];
  __shared__ float hb[15];

  const int tid=threadIdx.x;
  const int vbid = blockIdx.x;

  if (vbid >= 3752){
    // ------------------- ubits path -------------------
    int j = (vbid-3752)*256 + tid;
    if (j >= 2*R_TOT) return;
    int slot = j / HALF_R; int t = j - slot*HALF_R;
    uint32_t k0,k1;
    if      (slot==0){k0=kf00;k1=kf01;}
    else if (slot==1){k0=kb00;k1=kb01;}
    else if (slot==2){k0=kf10;k1=kf11;}
    else             {k0=kb10;k1=kb11;}
    uint32_t o0,o1;
    threefry(k0,k1,(uint32_t)t,(uint32_t)(t+HALF_R),&o0,&o1);
    ub[(size_t)slot*R_TOT+t]=o0;
    ub[(size_t)slot*R_TOT+t+HALF_R]=o1;
    return;
  }

  if (vbid >= 2728){
    // ------------------- label path -------------------
    double* gts=(double*)ush;                        // [128]
    double* hg =(double*)(ush+1024);                 // [32]
    int* wfg=(int*)(ush+1280); int* wbg=(int*)(ush+1296);
    const int lb=vbid-2728;
    const int img=lb>>9, blk=lb&511;
    if (tid<128) gts[tid]=(double)gt[img*128+tid];
    if (tid<32)  hg[tid]=__longlong_as_double((long long)highest[img*32+tid]);
    __syncthreads();
    int r=blk*256+tid;
    const bool ok=(r<R_TOT);
    int lab=-1, bi=0;
    if (ok){
      double a[4]; anchor_of(r,a);
      double best=-1.0; bool lq=false;
      #pragma unroll
      for (int g=0;g<32;g++){
        double v=iou_cf(gts[g*4],gts[g*4+1],gts[g*4+2],gts[g*4+3],a[0],a[1],a[2],a[3]);
        if (v>best){ best=v; bi=g; }
        if (hg[g]>0.0 && v==hg[g]) lq=true;
      }
      lab = lq ? 1 : (best>=0.7 ? 1 : (best>=0.3 ? -1 : 0));
      prelab [(size_t)img*R_TOT+r]=lab;
      matched[(size_t)img*R_TOT+r]=bi;
      labels [(size_t)img*R_TOT+r]=-1;
    }
    unsigned long long bf=__ballot(ok && lab==1);
    unsigned long long bb=__ballot(ok && lab==0);
    const int wid=tid>>6, lane=tid&63;
    if (lane==0){ wfg[wid]=__popcll(bf); wbg[wid]=__popcll(bb); }
    __syncthreads();
    if (tid==0){
      int fcnt=wfg[0]+wfg[1]+wfg[2]+wfg[3];
      int bcnt=wbg[0]+wbg[1]+wbg[2]+wbg[3];
      if (fcnt) atomicAdd(&counts[img*2+0],fcnt);
      if (bcnt) atomicAdd(&counts[img*2+1],bcnt);
    }
    return;
  }

  // ------------------- conv path -------------------
  const int cumt[6]={0,2048,2560,2688,2720,2728};
  const int Hs[5]={128,64,32,16,8}, Wl[5]={256,128,64,32,16};
  const int rbs[5]={0,98304,122880,129024,130560};
  const int lgx[5]={5,4,3,2,1};

  int bid=vbid;
  int lvl=0;
  while (lvl<4 && bid>=cumt[lvl+1]) lvl++;
  int t=bid-cumt[lvl];
  const int img=t&1; const int tt=t>>1;
  const int H=Hs[lvl], W=Wl[lvl], rbase=rbs[lvl];
  const int tx=tt&((1<<lgx[lvl])-1), ty=tt>>lgx[lvl];
  const int x0=tx*CTW, y0=ty*CTH;
  const float* f = lvl==0?f2: lvl==1?f3: lvl==2?f4: lvl==3?f5: f6;

  for (int i=tid;i<15*128;i+=256){
    int o=i>>7, c=i&127;
    hw[i]=(o<3)?ow[o*128+c]:dwt[(o-3)*128+c];
  }
  if (tid<15) hb[tid]=(tid<3)?ob[tid]:dbt[tid-3];

  const int c=tid&127, half=tid>>7;
  double acc[16];
  #pragma unroll
  for (int i=0;i<16;i++) acc[i]=0.0;

  const float* fimg = f + (size_t)img*128*H*W;

  const bool fin_act = (tid < 240);
  int ci_f=0,dy_f=0,dx_f=0; bool fin_valid=false;
  const float* fptr=fimg;
  if (fin_act){
    ci_f=tid/60; int rem=tid-ci_f*60; dy_f=rem/10; dx_f=rem-dy_f*10;
    int y=y0-1+dy_f, x=x0-1+dx_f;
    fin_valid = (y>=0&&y<H&&x>=0&&x<W);
    fptr = fimg + (size_t)ci_f*H*W + (fin_valid ? ((size_t)y*W+x) : 0);
  }
  const size_t fstep=(size_t)4*H*W;
  const float2* wsrc=(const float2*)cwTf;

  float fin_pf=0.f; float2 wpf[9];
  if (fin_act){ fin_pf = fin_valid ? *fptr : 0.f; fptr += fstep; }
  #pragma unroll
  for (int j2=0;j2<9;j2++) wpf[j2]=wsrc[tid+j2*256];

  for (int ci0=0; ci0<128; ci0+=4){
    __syncthreads();                         // prior compute done reading LDS
    if (fin_act) fshd[ci_f][dy_f][dx_f]=(double)fin_pf;
    { float2* wdst=(float2*)wshF;
      #pragma unroll
      for (int j2=0;j2<9;j2++) wdst[tid+j2*256]=wpf[j2]; }
    if (ci0+4<128){                          // issue next chunk (hidden by compute)
      if (fin_act){ fin_pf = fin_valid ? *fptr : 0.f; fptr += fstep; }
      const float2* wn = wsrc + (size_t)(ci0+4)*576;
      #pragma unroll
      for (int j2=0;j2<9;j2++) wpf[j2]=wn[tid+j2*256];
    }
    __syncthreads();                         // LDS ready
    #pragma unroll
    for (int ci=0;ci<4;ci++){
      double w9d[9];
      #pragma unroll
      for (int k=0;k<9;k++) w9d[k]=(double)wshF[(ci*9+k)*128 + c];
      #pragma unroll
      for (int irl=0;irl<4;irl++){
        int ir=half*2+irl;
        double rowb[10];
        #pragma unroll
        for (int q=0;q<10;q++) rowb[q]=fshd[ci][ir][q];
        #pragma unroll
        for (int orl=0;orl<2;orl++){
          int ky=irl-orl;
          if (ky<0||ky>2) continue;
          #pragma unroll
          for (int px=0;px<8;px++){
            double s=acc[orl*8+px];
            #pragma unroll
            for (int kx=0;kx<3;kx++) s += w9d[ky*3+kx]*rowb[px+kx];
            acc[orl*8+px]=s;
          }
        }
      }
    }
  }
  // ---- epilogue: two pixel halves (hshp [128][17], aliases wshF) ----
  double bc=(double)cb[c];
  __syncthreads();                           // wshF reads done
  if (half==0){
    #pragma unroll
    for (int pp=0;pp<16;pp++){
      double hv=acc[pp]+bc; if (hv<0.0) hv=0.0;
      hshp[c*17+pp]=hv;
    }
  }
  __syncthreads();
  for (int hp=0;hp<2;hp++){
    if (tid<240){
      int o=tid>>4, p=tid&15;
      double s=(double)hb[o];
      for (int c2=0;c2<128;c2++) s += (double)hw[o*128+c2]*hshp[c2*17+p];
      int pg=hp*16+p;
      int py=pg>>3, px=pg&7;
      int gy=y0+py, gx=x0+px;
      long long pix=(long long)gy*W+gx;
      size_t rb=(size_t)rbase+(size_t)pix*3;
      if (o<3) logits[(size_t)img*R_TOT+rb+o]=s;
      else { int a=(o-3)>>2, jj=(o-3)&3; dpred[((size_t)img*R_TOT+rb+a)*4+jj]=s; }
    }
    if (hp==0){
      __syncthreads();                       // heads done reading half 0
      if (half==1){
        #pragma unroll
        for (int pp=0;pp<16;pp++){
          double hv=acc[pp]+bc; if (hv<0.0) hv=0.0;
          hshp[c*17+pp]=hv;
        }
      }
      __syncthreads();                       // half 1 ready
    }
  }
}

// ============================================================================
// Kernel C (k_mid2, 1024 thr): [0,4): fg/bg sampling. [4,14): top-k with
// on-the-fly box decode. lvl0 topk blocks also init keepbuf to all-ones.
// ============================================================================
__global__ __launch_bounds__(1024) void k_mid2(const uint32_t* __restrict__ ub,
    const int* __restrict__ prelab, const int* __restrict__ counts,
    int* __restrict__ labels,
    const double* __restrict__ logits, const double* __restrict__ dpred,
    double* __restrict__ allS, double* __restrict__ allB,
    unsigned long long* __restrict__ keepbuf)
{
  __shared__ __align__(16) char buf[49152];
  __shared__ int hist[256];
  __shared__ int sI0, sI1;
  __shared__ int cnt;
  const int tid=threadIdx.x;

  if (blockIdx.x < 4){
    uint32_t* skey=(uint32_t*)buf; int* sidx=(int*)(buf+16384);
    const int img=blockIdx.x>>1, cls=blockIdx.x&1;
    const int cfg=counts[img*2+0], cbg=counts[img*2+1];
    const int num_fg=cfg<128?cfg:128;
    const int cap_bg=256-num_fg;
    const int num=cls?(cbg<cap_bg?cbg:cap_bg):num_fg;
    if (num<=0) return;
    const int want=cls?0:1;
    const int sel=want;
    const uint32_t* u=ub+(size_t)(img*2+cls)*R_TOT;
    const int* pl=prelab+(size_t)img*R_TOT;
    int* lab=labels+(size_t)img*R_TOT;

    for (int b=tid;b<256;b+=1024) hist[b]=0;
    if (tid==0) cnt=0;
    __syncthreads();
    #pragma unroll 4
    for (int r=tid;r<R_TOT;r+=1024){
      int plr = pl[r];
      uint32_t key = u[r]>>9;
      if (plr==want) atomicAdd(&hist[key>>15],1);
    }
    __syncthreads();
    hist_select(hist, num, tid, &sI0, &sI1);
    const uint32_t bsel=(uint32_t)sI0; const int kneed=sI1;
    #pragma unroll 4
    for (int r=tid;r<R_TOT;r+=1024){
      int plr = pl[r];
      uint32_t key = u[r]>>9;
      if (plr==want){
        uint32_t t8=key>>15;
        if (t8<bsel) lab[r]=sel;
        else if (t8==bsel){ int p=atomicAdd(&cnt,1); if (p<4096){ skey[p]=key; sidx[p]=r; } }
      }
    }
    __syncthreads();
    int n=cnt<4096?cnt:4096;
    for (int i=tid;i<4096;i+=1024) if (i>=n){ skey[i]=0xFFFFFFFFu; sidx[i]=0x7FFFFFFF; }
    bitonic_asc_u(skey,sidx,4096,tid,1024);
    int take = kneed<n?kneed:n;
    for (int i=tid;i<take;i+=1024) lab[sidx[i]]=sel;
  } else {
    double* sv=(double*)buf; int* si=(int*)(buf+32768);
    const int Rl[5]   ={98304,24576,6144,1536,384};
    const int kl[5]   ={2000,2000,2000,1536,384};
    const int lbase[5]={0,98304,122880,129024,130560};
    const int loff[5] ={0,2000,4000,6000,7536};
    const int bb=blockIdx.x-4;
    const int lvl=bb%5, img=bb/5;
    if (lvl==0 && tid<124) keepbuf[img*124+tid]=~0ull;   // init for k_post
    const int Rn=Rl[lvl], K=kl[lvl];
    const double* lg=logits+(size_t)img*R_TOT+lbase[lvl];

    unsigned long long chosen=0; int kneed=K;
    for (int ps=7; ps>=6; --ps){
      int shift=ps*8;
      for (int b=tid;b<256;b+=1024) hist[b]=0;
      __syncthreads();
      #pragma unroll 4
      for (int r=tid;r<Rn;r+=1024){
        unsigned long long ik=~mono64(lg[r]);
        bool okp=(ps==7)||((ik>>(shift+8))==(chosen>>(shift+8)));
        if (okp) atomicAdd(&hist[(int)((ik>>shift)&255)],1);
      }
      __syncthreads();
      hist_select(hist, kneed, tid, &sI0, &sI1);
      chosen = chosen | ((unsigned long long)sI0<<shift);
      kneed  = sI1;
      __syncthreads();
    }
    const unsigned long long lim = chosen | 0xFFFFFFFFFFFFull;
    if (tid==0) cnt=0;
    __syncthreads();
    #pragma unroll 4
    for (int r=tid;r<Rn;r+=1024){
      unsigned long long ik=~mono64(lg[r]);
      if (ik<=lim){ int p=atomicAdd(&cnt,1); if (p<4096){ sv[p]=lg[r]; si[p]=r; } }
    }
    __syncthreads();
    int n=cnt<4096?cnt:4096;
    for (int i=tid;i<4096;i+=1024) if (i>=n){ sv[i]=-HUGE_VAL; si[i]=0x7FFFFFFF; }
    bitonic_desc(sv,si,4096,tid,1024);
    for (int j=tid;j<K;j+=1024){
      double v=sv[j]; int r=si[j];
      size_t slot=(size_t)img*TOTK+loff[lvl]+j;
      allS[slot]=v;
      int ridx=lbase[lvl]+r;
      double bx[4];
      decode_box(ridx, dpred+((size_t)img*R_TOT+ridx)*4, bx);
      allB[slot*4+0]=bx[0]; allB[slot*4+1]=bx[1]; allB[slot*4+2]=bx[2]; allB[slot*4+3]=bx[3];
    }
  }
}

// ============================================================================
// Kernel D (k_mid3): [0,1980): NMS mask, 8 rows/block, boxes in LDS.
//                    [1980,2236): loss partials.
// ============================================================================
__global__ __launch_bounds__(256) void k_mid3(const double* __restrict__ allB,
    unsigned long long* __restrict__ msk,
    const double* __restrict__ logits, const double* __restrict__ dpred,
    const float* __restrict__ gt, const int* __restrict__ labels,
    const int* __restrict__ matched, double* __restrict__ part)
{
  const int bx=blockIdx.x, tid=threadIdx.x;
  if (bx < 1980){
    __shared__ double Bsh[8000];
    const int kl[5]  ={2000,2000,2000,1536,384};
    const int loff[5]={0,2000,4000,6000,7536};
    const int rbc[6] ={0,250,500,750,942,990};
    const int img = bx/990; int t = bx - img*990;
    int lvl=0; while (lvl<4 && t>=rbc[lvl+1]) lvl++;
    const int i0=(t-rbc[lvl])*8;
    const int K=kl[lvl]; const int nw=(K+63)>>6;
    const double* B=allB+(size_t)(img*TOTK+loff[lvl])*4;
    for (int q=tid;q<K*4;q+=256) Bsh[q]=B[q];
    __syncthreads();
    const int wv=tid>>6, lane=tid&63;
    for (int rr=0;rr<8;rr++){
      int i=i0+rr;
      if (i>=K) break;
      const double bi0=Bsh[i*4],bi1=Bsh[i*4+1],bi2=Bsh[i*4+2],bi3=Bsh[i*4+3];
      const double areai=(bi2-bi0)*(bi3-bi1);
      for (int w=wv;w<nw;w+=4){
        int j=w*64+lane;
        bool pred=false;
        if (j<K && j>i){
          double a0=Bsh[j*4],a1=Bsh[j*4+1],a2=Bsh[j*4+2],a3=Bsh[j*4+3];
          double lt0=fmax(bi0,a0), lt1=fmax(bi1,a1);
          double rb0=fmin(bi2,a2), rb1=fmin(bi3,a3);
          double ww=rb0-lt0; if (ww<0.0) ww=0.0;
          double hh=rb1-lt1; if (hh<0.0) hh=0.0;
          double inter=ww*hh;
          double uni=areai+(a2-a0)*(a3-a1)-inter;
          double iou=inter>0.0?inter/uni:0.0;
          pred = iou>0.7;
        }
        unsigned long long m=__ballot(pred);
        if (lane==0) msk[((size_t)img*TOTK+loff[lvl]+i)*32+w]=m;
      }
    }
  } else {
    const int bid2=bx-1980;
    double cls=0.0, loc=0.0;
    for (int idx=bid2*256+tid; idx<2*R_TOT; idx+=256*256){
      int l=labels[idx];
      if (l<0) continue;
      double x=logits[idx];
      double fgv=(l==1)?1.0:0.0;
      cls += fmax(x,0.0)-x*fgv+log1p(exp(-fabs(x)));
      if (l==1){
        int img=idx/R_TOT, r=idx-img*R_TOT;
        double a[4]; anchor_of(r,a);
        int m=matched[idx];
        const float* g=gt+img*128+m*4;
        double sw=a[2]-a[0], sh=a[3]-a[1];
        double scx=a[0]+0.5*sw, scy=a[1]+0.5*sh;
        double tw=(double)g[2]-(double)g[0], th=(double)g[3]-(double)g[1];
        double tcx=(double)g[0]+0.5*tw, tcy=(double)g[1]+0.5*th;
        double d0=(tcx-scx)/sw, d1=(tcy-scy)/sh;
        double d2=log(tw/sw), d3=log(th/sh);
        const double* dp=dpred+(size_t)idx*4;
        loc += fabs(dp[0]-d0)+fabs(dp[1]-d1)+fabs(dp[2]-d2)+fabs(dp[3]-d3);
      }
    }
    __shared__ double sc[256], sl[256];
    sc[tid]=cls; sl[tid]=loc; __syncthreads();
    for (int s=128;s>0;s>>=1){
      if (tid<s){ sc[tid]+=sc[tid+s]; sl[tid]+=sl[tid+s]; }
      __syncthreads();
    }
    if (tid==0){ part[bid2*2]=sc[0]; part[bid2*2+1]=sl[0]; }
  }
}

// ============================================================================
// Kernel E (k_post, 13 blocks x 256 thr — co-resident => spin-flags safe):
//  [0,10): register-resolve greedy NMS scan -> keepbuf (atomicAnd) -> flags++.
//  [10,12): per-image top-1000 after spin flags[img]==5.
//  [12]:   loss final reduce.
// ============================================================================
__global__ __launch_bounds__(256) void k_post(const double* __restrict__ allB,
    const double* __restrict__ allS, const unsigned long long* __restrict__ msk,
    const double* __restrict__ part, int* __restrict__ flags,
    unsigned long long* __restrict__ keepbuf, float* __restrict__ out)
{
  const int tid=threadIdx.x, bx=blockIdx.x;
  const int kl[5]  ={2000,2000,2000,1536,384};
  const int loff[5]={0,2000,4000,6000,7536};

  if (bx < 10){
    // ---------------- register-resolve greedy NMS scan ----------------
    if (tid >= 64) return;
    const int lvl=bx%5, img=bx/5;
    const int K=kl[lvl], off=loff[lvl], nw=(K+63)>>6;
    const int lane=tid;
    const double* B=allB+(size_t)(img*TOTK+off)*4;
    const unsigned long long* M=msk+((size_t)img*TOTK+off)*32;
    unsigned long long keep=0ull;
    if (lane<nw){
      for (int b=0;b<64;b++){
        int j=lane*64+b;
        if (j<K){
          double x1=B[(size_t)j*4],y1=B[(size_t)j*4+1],x2=B[(size_t)j*4+2],y2=B[(size_t)j*4+3];
          if ((x2-x1)>0.0 && (y2-y1)>0.0) keep|=(1ull<<b);
        }
      }
    }
    // Per 64-row group w:
    //  (1) all lanes load the group's 64 diagonal words into REGISTERS
    //      (uniform-address broadcast loads, fully unrolled -> static idx);
    //  (2) serial resolve is pure in-register VALU (no shfl in the chain);
    //  (3) bulk OR-suppression of kept rows onto later words (independent
    //      coalesced loads). Exact greedy semantics (diag has bits>b only;
    //      cross-group masks have j>i only).
    for (int w=0; w<nw; w++){
      unsigned long long cur = __shfl(keep, w);   // one broadcast per group
      unsigned long long d[64];
      const int rowbase = w*64;
      #pragma unroll
      for (int b=0;b<64;b++){
        int row = rowbase + b;
        d[b] = (row<K) ? M[(size_t)row*32+w] : 0ull;
      }
      #pragma unroll
      for (int b=0;b<64;b++){
        unsigned long long m = ((cur>>b)&1ull) ? ~d[b] : ~0ull;
        cur &= m;
      }
      if (lane==w) keep=cur;
      if (lane>w && lane<nw){
        unsigned long long sup=0ull;
        #pragma unroll
        for (int b=0;b<64;b++){
          if ((cur>>b)&1ull) sup |= M[(size_t)(rowbase+b)*32+lane];
        }
        keep &= ~sup;
      }
    }
    // publish suppression to keepbuf (global bit positions off+lane*64..)
    if (lane<nw){
      int nvalid = K - lane*64; if (nvalid>64) nvalid=64;
      unsigned long long vm = (nvalid>=64) ? ~0ull : ((1ull<<nvalid)-1ull);
      unsigned long long cbits = (~keep) & vm;     // bits to clear
      int gbase = off + lane*64;
      int w0 = gbase>>6, sh = gbase&63;
      unsigned long long* kb = keepbuf + (size_t)img*124;
      if (sh==0){
        if (cbits) atomicAnd(&kb[w0], ~cbits);
      } else {
        unsigned long long lo = cbits << sh;
        unsigned long long hi = cbits >> (64-sh);
        if (lo) atomicAnd(&kb[w0],   ~lo);
        if (hi) atomicAnd(&kb[w0+1], ~hi);
      }
    }
    __threadfence();
    if (tid==0) atomicAdd(&flags[img],1);
    return;
  }

  if (bx < 12){
    // ---------------- per-image top-1000 (256 threads) ----------------
    const int img=bx-10;
    if (tid==0){
      while (atomicAdd(&flags[img],0) < 5) __builtin_amdgcn_s_sleep(8);
    }
    __syncthreads();
    __threadfence();
    __shared__ unsigned long long kbl[124];
    if (tid<124) kbl[tid]=atomicAdd(&keepbuf[(size_t)img*124+tid],0ull);
    __syncthreads();
    const double* sarr=allS+(size_t)img*TOTK;
    __shared__ int hist[256];
    __shared__ int sI0, sI1;
    __shared__ double sv[4096]; __shared__ int si[4096]; __shared__ int cnt;

    unsigned long long chosen=0; int kneed=1000;
    for (int ps=7; ps>=6; --ps){
      int shift=ps*8;
      hist[tid]=0;
      __syncthreads();
      for (int r=tid;r<TOTK;r+=256){
        bool kept = (kbl[r>>6]>>(r&63))&1ull;
        double val = kept ? sarr[r] : -HUGE_VAL;
        unsigned long long ik=~mono64(val);
        bool okp=(ps==7)||((ik>>(shift+8))==(chosen>>(shift+8)));
        if (okp) atomicAdd(&hist[(int)((ik>>shift)&255)],1);
      }
      __syncthreads();
      hist_select(hist, kneed, tid, &sI0, &sI1);
      chosen = chosen | ((unsigned long long)sI0<<shift);
      kneed  = sI1;
      __syncthreads();
    }
    const unsigned long long lim = chosen | 0xFFFFFFFFFFFFull;
    if (tid==0) cnt=0;
    __syncthreads();
    for (int r=tid;r<TOTK;r+=256){
      bool kept = (kbl[r>>6]>>(r&63))&1ull;
      double val = kept ? sarr[r] : -HUGE_VAL;
      unsigned long long ik=~mono64(val);
      if (ik<=lim){ int p=atomicAdd(&cnt,1); if (p<4096){ sv[p]=val; si[p]=r; } }
    }
    __syncthreads();
    int n=cnt<4096?cnt:4096;
    for (int i=tid;i<4096;i+=256) if (i>=n){ sv[i]=-HUGE_VAL; si[i]=0x7FFFFFFF; }
    bitonic_desc(sv,si,4096,tid,256);
    for (int j=tid;j<1000;j+=256){
      out[8000+img*1000+j]=(float)sv[j];
      int idx=si[j];
      const double* b=allB+((size_t)img*TOTK+idx)*4;
      float* ob=out+((size_t)img*1000+j)*4;
      ob[0]=(float)b[0]; ob[1]=(float)b[1]; ob[2]=(float)b[2]; ob[3]=(float)b[3];
    }
    return;
  }

  // ---------------- loss final reduce ----------------
  __shared__ double sc[256], sl[256];
  sc[tid]=part[tid*2]; sl[tid]=part[tid*2+1];
  __syncthreads();
  for (int s=128;s>0;s>>=1){
    if (tid<s){ sc[tid]+=sc[tid+s]; sl[tid]+=sl[tid+s]; }
    __syncthreads();
  }
  if (tid==0){ out[10000]=(float)(sc[0]/512.0); out[10001]=(float)(sl[0]/512.0); }
}

// ============================================================================
// Host launcher
// ============================================================================
extern "C" void kernel_launch(void* const* d_in, const int* in_sizes, int n_in,
                              void* d_out, int out_size, void* d_ws, size_t ws_size,
                              hipStream_t stream)
{
  (void)in_sizes; (void)n_in; (void)out_size;
  const float* feats[5];
  for (int i=0;i<5;i++) feats[i]=(const float*)d_in[i];
  const float* gt =(const float*)d_in[5];
  const float* cw =(const float*)d_in[6];
  const float* cb =(const float*)d_in[7];
  const float* ow =(const float*)d_in[8];
  const float* ob =(const float*)d_in[9];
  const float* dwt=(const float*)d_in[10];
  const float* dbt=(const float*)d_in[11];
  float* out=(float*)d_out;

  char* p=(char*)d_ws;
  auto carve=[&](size_t nbytes)->char*{ char* q=p; p += (nbytes+255)&~(size_t)255; return q; };
  double* logits =(double*)carve(2ull*R_TOT*8);
  double* dpred  =(double*)carve(2ull*R_TOT*4*8);
  float* cwTf    =(float*)carve(147456ull*4);
  uint32_t* ub   =(uint32_t*)carve(4ull*R_TOT*4);
  int* prelab    =(int*)carve(2ull*R_TOT*4);
  int* matched   =(int*)carve(2ull*R_TOT*4);
  int* labels    =(int*)carve(2ull*R_TOT*4);
  unsigned long long* highest=(unsigned long long*)carve(2*32*8);   // +0:   512B
  int* counts    =(int*)carve(256);                                  // +512: 256B
  int* flags     =(int*)carve(256);                                  // +768: 256B
  double* allS   =(double*)carve(2ull*TOTK*8);
  double* allB   =(double*)carve(2ull*TOTK*4*8);
  unsigned long long* msk=(unsigned long long*)carve(2ull*TOTK*32*8);
  double* part   =(double*)carve(256*2*8);
  unsigned long long* keepbuf=(unsigned long long*)carve(2*124*8);   // init in k_mid2
  if ((size_t)(p-(char*)d_ws) > ws_size) return;

  hipMemsetAsync(highest, 0, 1024, stream);  // highest + counts + flags (contiguous)

  uint32_t a0,b0,a1,b1;
  threefry(0u,42u,0u,2u,&a0,&b0);
  threefry(0u,42u,1u,3u,&a1,&b1);
  uint32_t kf00,kf01,kb00,kb01,kf10,kf11,kb10,kb11;
  { uint32_t c0,d0,c1,d1;
    threefry(a0,a1,0u,2u,&c0,&d0); threefry(a0,a1,1u,3u,&c1,&d1);
    kf00=c0; kf01=c1; kb00=d0; kb01=d1;
    threefry(b0,b1,0u,2u,&c0,&d0); threefry(b0,b1,1u,3u,&c1,&d1);
    kf10=c0; kf11=c1; kb10=d0; kb11=d1; }

  k_pre<<<704, 256, 0, stream>>>(cw, cwTf, gt, highest);
  k_conv_label<<<4775, 256, 0, stream>>>(feats[0],feats[1],feats[2],feats[3],feats[4],
      cwTf,cb,ow,ob,dwt,dbt, logits, dpred,
      gt, highest, prelab, matched, labels, counts,
      ub, kf00,kf01,kb00,kb01,kf10,kf11,kb10,kb11);
  k_mid2<<<14, 1024, 0, stream>>>(ub, prelab, counts, labels, logits, dpred, allS, allB, keepbuf);
  k_mid3<<<2236, 256, 0, stream>>>(allB, msk, logits, dpred, gt, labels, matched, part);
  k_post<<<13, 256, 0, stream>>>(allB, allS, msk, part, flags, keepbuf, out);
}

// Round 15
// 1404.683 us; speedup vs baseline: 1.4875x; 1.4875x over previous
//
#include <hip/hip_runtime.h>
#include <stdint.h>
#include <math.h>

// ============================================================================
// RPN forward (detectron2-style) on MI355X — fp64 ordering-exact pipeline.
// R15: NMS scan = wave-parallel ballot fixed-point. Mask made symmetric
// (iou is bitwise-symmetric) so lane L's "suppressors below me" word is its
// own row's lower bits -> greedy kept set is the unique fixed point of
// kmask = ballot(valid && (m_lo & kmask)==0). No shfl/loads in the chain
// (R13's shfl chain and R14's spilled d[64] both cost 0.5-1.3ms at the
// throttled clocks of a single-wave kernel).
// ============================================================================

#define R_TOT   130944
#define HALF_R  65472
#define TOTK    7920
#define SCALE_CLAMP 4.135166556742356  // log(1000/16)

// ---------------- threefry2x32-20 (JAX-compatible) ----------------
__host__ __device__ inline void threefry(uint32_t k0, uint32_t k1,
                                         uint32_t x0, uint32_t x1,
                                         uint32_t* o0, uint32_t* o1)
{
  uint32_t ks[3]; ks[0]=k0; ks[1]=k1; ks[2]=k0^k1^0x1BD11BDAu;
  x0 += ks[0]; x1 += ks[1];
  const uint32_t rot0[4] = {13u,15u,26u,6u};
  const uint32_t rot1[4] = {17u,29u,16u,24u};
  for (int i = 0; i < 5; i++){
    const uint32_t* rot = (i & 1) ? rot1 : rot0;
    for (int q = 0; q < 4; q++){
      x0 += x1;
      x1 = (x1 << rot[q]) | (x1 >> (32u - rot[q]));
      x1 ^= x0;
    }
    x0 += ks[(i+1)%3];
    x1 += ks[(i+2)%3] + (uint32_t)(i+1);
  }
  *o0 = x0; *o1 = x1;
}

// ---------------- helpers ----------------
__device__ inline unsigned long long mono64(double v){
  unsigned long long b = (unsigned long long)__double_as_longlong(v);
  return (b & 0x8000000000000000ull) ? ~b : (b | 0x8000000000000000ull);
}

__device__ __forceinline__ double iou_cf(double g0,double g1,double g2,double g3,
                                         double a0,double a1,double a2,double a3){
  #pragma clang fp contract(off)
  double lt0 = fmax(g0,a0), lt1 = fmax(g1,a1);
  double rb0 = fmin(g2,a2), rb1 = fmin(g3,a3);
  double w = rb0-lt0; if (w<0.0) w=0.0;
  double h = rb1-lt1; if (h<0.0) h=0.0;
  double inter = w*h;
  double aa = (g2-g0)*(g3-g1);
  double ab = (a2-a0)*(a3-a1);
  double uni = aa+ab-inter;
  return inter>0.0 ? inter/uni : 0.0;
}

__device__ __forceinline__ void anchor_of(int r, double* o){
  #pragma clang fp contract(off)
  const int    base[5]={0,98304,122880,129024,130560};
  const int    Wl[5]  ={256,128,64,32,16};
  const double strd[5]={4.0,8.0,16.0,32.0,64.0};
  const double size[5]={32.0,64.0,128.0,256.0,512.0};
  const double ratio[3]={0.5,1.0,2.0};
  int l=0; while (l<4 && r>=base[l+1]) l++;
  int rr=r-base[l]; int pix=rr/3; int a=rr-pix*3;
  int x=pix%Wl[l], y=pix/Wl[l];
  double w=sqrt(size[l]*size[l]/ratio[a]);
  double h=w*ratio[a];
  double sx=(double)x*strd[l], sy=(double)y*strd[l];
  o[0]=sx-0.5*w; o[1]=sy-0.5*h; o[2]=sx+0.5*w; o[3]=sy+0.5*h;
}

// apply_deltas + clip
__device__ __forceinline__ void decode_box(int ridx, const double* __restrict__ d,
                                           double* __restrict__ o){
  double a[4]; anchor_of(ridx,a);
  double w=a[2]-a[0], h=a[3]-a[1];
  double cx=a[0]+0.5*w, cy=a[1]+0.5*h;
  double dw=fmin(d[2],SCALE_CLAMP), dh=fmin(d[3],SCALE_CLAMP);
  double pcx=d[0]*w+cx, pcy=d[1]*h+cy;
  double pw=exp(dw)*w, ph=exp(dh)*h;
  double x1=pcx-0.5*pw, y1=pcy-0.5*ph;
  double x2=pcx+0.5*pw, y2=pcy+0.5*ph;
  o[0]=fmin(fmax(x1,0.0),1024.0); o[1]=fmin(fmax(y1,0.0),512.0);
  o[2]=fmin(fmax(x2,0.0),1024.0); o[3]=fmin(fmax(y2,0.0),512.0);
}

__device__ inline void bitonic_desc(double* sv, int* si, int M, int tid, int nthr){
  for (int k=2;k<=M;k<<=1)
    for (int j=k>>1;j>0;j>>=1){
      __syncthreads();
      for (int i=tid;i<M;i+=nthr){
        int ixj=i^j;
        if (ixj>i){
          double va=sv[i], vb=sv[ixj]; int ia=si[i], ib=si[ixj];
          bool before = (va>vb) || (va==vb && ia<ib);
          bool up = ((i&k)==0);
          if (up ? !before : before){ sv[i]=vb; sv[ixj]=va; si[i]=ib; si[ixj]=ia; }
        }
      }
    }
  __syncthreads();
}

__device__ inline void bitonic_asc_u(uint32_t* sk, int* si, int M, int tid, int nthr){
  for (int k=2;k<=M;k<<=1)
    for (int j=k>>1;j>0;j>>=1){
      __syncthreads();
      for (int i=tid;i<M;i+=nthr){
        int ixj=i^j;
        if (ixj>i){
          uint32_t ka=sk[i], kb=sk[ixj]; int ia=si[i], ib=si[ixj];
          bool before = (ka<kb) || (ka==kb && ia<ib);
          bool up = ((i&k)==0);
          if (up ? !before : before){ sk[i]=kb; sk[ixj]=ka; si[i]=ib; si[ixj]=ia; }
        }
      }
    }
  __syncthreads();
}

// Parallel select over hist[256] (in-place inclusive scan). blockDim >= 256.
__device__ inline void hist_select(int* hist, int kneed, int tid,
                                   int* shb, int* shk){
  for (int off=1; off<256; off<<=1){
    int v=0;
    if (tid<256 && tid>=off) v=hist[tid-off];
    __syncthreads();
    if (tid<256) hist[tid]+=v;
    __syncthreads();
  }
  if (tid<256){
    int prev = tid ? hist[tid-1] : 0;
    if (prev < kneed && kneed <= hist[tid]){ *shb=tid; *shk=kneed-prev; }
    if (tid==255 && kneed > hist[255]){ *shb=255; *shk=kneed-hist[254]; }
  }
  __syncthreads();
}

// ============================================================================
// Kernel A (k_pre): [0,576): weight permute cw->cwTf[ci][k9][cc] f32.
//                   [576,704): per-gt max IoU (gtmax).
// ============================================================================
__global__ __launch_bounds__(256) void k_pre(const float* __restrict__ cw,
    float* __restrict__ cwTf, const float* __restrict__ gt,
    unsigned long long* __restrict__ highest)
{
  const int bx=blockIdx.x, tid=threadIdx.x;
  if (bx < 576){
    int o = bx*256 + tid;
    if (o >= 147456) return;
    int cc = o & 127; int t = o >> 7;
    int k9 = t % 9;  int ci = t / 9;
    cwTf[(size_t)(ci*9+k9)*128 + cc] = cw[(size_t)cc*1152 + ci*9 + k9];
  } else {
    __shared__ double gts[128];
    __shared__ unsigned long long lmax[32];
    const int gb=bx-576;
    const int img=gb>>6, b=gb&63;
    if (tid<128) gts[tid]=(double)gt[img*128+tid];
    if (tid<32) lmax[tid]=0ull;
    __syncthreads();
    double gm[32];
    #pragma unroll
    for (int g=0;g<32;g++) gm[g]=0.0;
    for (int r=b*256+tid; r<R_TOT; r+=64*256){
      double a[4]; anchor_of(r,a);
      #pragma unroll
      for (int g=0;g<32;g++){
        double v=iou_cf(gts[g*4],gts[g*4+1],gts[g*4+2],gts[g*4+3],a[0],a[1],a[2],a[3]);
        gm[g]=fmax(gm[g],v);
      }
    }
    #pragma unroll
    for (int g=0;g<32;g++){
      double v=gm[g];
      #pragma unroll
      for (int off=1; off<64; off<<=1) v=fmax(v,__shfl_xor(v,off));
      if ((tid&63)==0) atomicMax(&lmax[g],(unsigned long long)__double_as_longlong(v));
    }
    __syncthreads();
    if (tid<32) atomicMax(&highest[img*32+tid], lmax[tid]);
  }
}

// ============================================================================
// Kernel B (k_conv_label): [0,2728): conv+heads. [2728,3752): labels.
// [3752,4775): threefry ubits.
// ============================================================================
#define CTH 4
#define CTW 8

__global__ __launch_bounds__(256,3) void k_conv_label(
    const float* __restrict__ f2, const float* __restrict__ f3,
    const float* __restrict__ f4, const float* __restrict__ f5,
    const float* __restrict__ f6,
    const float* __restrict__ cwTf, const float* __restrict__ cb,
    const float* __restrict__ ow, const float* __restrict__ ob,
    const float* __restrict__ dwt, const float* __restrict__ dbt,
    double* __restrict__ logits, double* __restrict__ dpred,
    const float* __restrict__ gt, const unsigned long long* __restrict__ highest,
    int* __restrict__ prelab, int* __restrict__ matched,
    int* __restrict__ labels, int* __restrict__ counts,
    uint32_t* __restrict__ ub,
    uint32_t kf00,uint32_t kf01,uint32_t kb00,uint32_t kb01,
    uint32_t kf10,uint32_t kf11,uint32_t kb10,uint32_t kb11)
{
  __shared__ double fshd[4][6][12];
  __shared__ __align__(16) char ush[18432];   // wshF [4][9][128] f32 / hshp [128][17] dbl / label arrays
  float*  wshF = (float*)ush;
  double* hshp = (double*)ush;
  __shared__ float hw[15*128];
  __shared__ float hb[15];

  const int tid=threadIdx.x;
  const int vbid = blockIdx.x;

  if (vbid >= 3752){
    // ------------------- ubits path -------------------
    int j = (vbid-3752)*256 + tid;
    if (j >= 2*R_TOT) return;
    int slot = j / HALF_R; int t = j - slot*HALF_R;
    uint32_t k0,k1;
    if      (slot==0){k0=kf00;k1=kf01;}
    else if (slot==1){k0=kb00;k1=kb01;}
    else if (slot==2){k0=kf10;k1=kf11;}
    else             {k0=kb10;k1=kb11;}
    uint32_t o0,o1;
    threefry(k0,k1,(uint32_t)t,(uint32_t)(t+HALF_R),&o0,&o1);
    ub[(size_t)slot*R_TOT+t]=o0;
    ub[(size_t)slot*R_TOT+t+HALF_R]=o1;
    return;
  }

  if (vbid >= 2728){
    // ------------------- label path -------------------
    double* gts=(double*)ush;                        // [128]
    double* hg =(double*)(ush+1024);                 // [32]
    int* wfg=(int*)(ush+1280); int* wbg=(int*)(ush+1296);
    const int lb=vbid-2728;
    const int img=lb>>9, blk=lb&511;
    if (tid<128) gts[tid]=(double)gt[img*128+tid];
    if (tid<32)  hg[tid]=__longlong_as_double((long long)highest[img*32+tid]);
    __syncthreads();
    int r=blk*256+tid;
    const bool ok=(r<R_TOT);
    int lab=-1, bi=0;
    if (ok){
      double a[4]; anchor_of(r,a);
      double best=-1.0; bool lq=false;
      #pragma unroll
      for (int g=0;g<32;g++){
        double v=iou_cf(gts[g*4],gts[g*4+1],gts[g*4+2],gts[g*4+3],a[0],a[1],a[2],a[3]);
        if (v>best){ best=v; bi=g; }
        if (hg[g]>0.0 && v==hg[g]) lq=true;
      }
      lab = lq ? 1 : (best>=0.7 ? 1 : (best>=0.3 ? -1 : 0));
      prelab [(size_t)img*R_TOT+r]=lab;
      matched[(size_t)img*R_TOT+r]=bi;
      labels [(size_t)img*R_TOT+r]=-1;
    }
    unsigned long long bf=__ballot(ok && lab==1);
    unsigned long long bb=__ballot(ok && lab==0);
    const int wid=tid>>6, lane=tid&63;
    if (lane==0){ wfg[wid]=__popcll(bf); wbg[wid]=__popcll(bb); }
    __syncthreads();
    if (tid==0){
      int fcnt=wfg[0]+wfg[1]+wfg[2]+wfg[3];
      int bcnt=wbg[0]+wbg[1]+wbg[2]+wbg[3];
      if (fcnt) atomicAdd(&counts[img*2+0],fcnt);
      if (bcnt) atomicAdd(&counts[img*2+1],bcnt);
    }
    return;
  }

  // ------------------- conv path -------------------
  const int cumt[6]={0,2048,2560,2688,2720,2728};
  const int Hs[5]={128,64,32,16,8}, Wl[5]={256,128,64,32,16};
  const int rbs[5]={0,98304,122880,129024,130560};
  const int lgx[5]={5,4,3,2,1};

  int bid=vbid;
  int lvl=0;
  while (lvl<4 && bid>=cumt[lvl+1]) lvl++;
  int t=bid-cumt[lvl];
  const int img=t&1; const int tt=t>>1;
  const int H=Hs[lvl], W=Wl[lvl], rbase=rbs[lvl];
  const int tx=tt&((1<<lgx[lvl])-1), ty=tt>>lgx[lvl];
  const int x0=tx*CTW, y0=ty*CTH;
  const float* f = lvl==0?f2: lvl==1?f3: lvl==2?f4: lvl==3?f5: f6;

  for (int i=tid;i<15*128;i+=256){
    int o=i>>7, c=i&127;
    hw[i]=(o<3)?ow[o*128+c]:dwt[(o-3)*128+c];
  }
  if (tid<15) hb[tid]=(tid<3)?ob[tid]:dbt[tid-3];

  const int c=tid&127, half=tid>>7;
  double acc[16];
  #pragma unroll
  for (int i=0;i<16;i++) acc[i]=0.0;

  const float* fimg = f + (size_t)img*128*H*W;

  const bool fin_act = (tid < 240);
  int ci_f=0,dy_f=0,dx_f=0; bool fin_valid=false;
  const float* fptr=fimg;
  if (fin_act){
    ci_f=tid/60; int rem=tid-ci_f*60; dy_f=rem/10; dx_f=rem-dy_f*10;
    int y=y0-1+dy_f, x=x0-1+dx_f;
    fin_valid = (y>=0&&y<H&&x>=0&&x<W);
    fptr = fimg + (size_t)ci_f*H*W + (fin_valid ? ((size_t)y*W+x) : 0);
  }
  const size_t fstep=(size_t)4*H*W;
  const float2* wsrc=(const float2*)cwTf;

  float fin_pf=0.f; float2 wpf[9];
  if (fin_act){ fin_pf = fin_valid ? *fptr : 0.f; fptr += fstep; }
  #pragma unroll
  for (int j2=0;j2<9;j2++) wpf[j2]=wsrc[tid+j2*256];

  for (int ci0=0; ci0<128; ci0+=4){
    __syncthreads();                         // prior compute done reading LDS
    if (fin_act) fshd[ci_f][dy_f][dx_f]=(double)fin_pf;
    { float2* wdst=(float2*)wshF;
      #pragma unroll
      for (int j2=0;j2<9;j2++) wdst[tid+j2*256]=wpf[j2]; }
    if (ci0+4<128){                          // issue next chunk (hidden by compute)
      if (fin_act){ fin_pf = fin_valid ? *fptr : 0.f; fptr += fstep; }
      const float2* wn = wsrc + (size_t)(ci0+4)*576;
      #pragma unroll
      for (int j2=0;j2<9;j2++) wpf[j2]=wn[tid+j2*256];
    }
    __syncthreads();                         // LDS ready
    #pragma unroll
    for (int ci=0;ci<4;ci++){
      double w9d[9];
      #pragma unroll
      for (int k=0;k<9;k++) w9d[k]=(double)wshF[(ci*9+k)*128 + c];
      #pragma unroll
      for (int irl=0;irl<4;irl++){
        int ir=half*2+irl;
        double rowb[10];
        #pragma unroll
        for (int q=0;q<10;q++) rowb[q]=fshd[ci][ir][q];
        #pragma unroll
        for (int orl=0;orl<2;orl++){
          int ky=irl-orl;
          if (ky<0||ky>2) continue;
          #pragma unroll
          for (int px=0;px<8;px++){
            double s=acc[orl*8+px];
            #pragma unroll
            for (int kx=0;kx<3;kx++) s += w9d[ky*3+kx]*rowb[px+kx];
            acc[orl*8+px]=s;
          }
        }
      }
    }
  }
  // ---- epilogue: two pixel halves (hshp [128][17], aliases wshF) ----
  double bc=(double)cb[c];
  __syncthreads();                           // wshF reads done
  if (half==0){
    #pragma unroll
    for (int pp=0;pp<16;pp++){
      double hv=acc[pp]+bc; if (hv<0.0) hv=0.0;
      hshp[c*17+pp]=hv;
    }
  }
  __syncthreads();
  for (int hp=0;hp<2;hp++){
    if (tid<240){
      int o=tid>>4, p=tid&15;
      double s=(double)hb[o];
      for (int c2=0;c2<128;c2++) s += (double)hw[o*128+c2]*hshp[c2*17+p];
      int pg=hp*16+p;
      int py=pg>>3, px=pg&7;
      int gy=y0+py, gx=x0+px;
      long long pix=(long long)gy*W+gx;
      size_t rb=(size_t)rbase+(size_t)pix*3;
      if (o<3) logits[(size_t)img*R_TOT+rb+o]=s;
      else { int a=(o-3)>>2, jj=(o-3)&3; dpred[((size_t)img*R_TOT+rb+a)*4+jj]=s; }
    }
    if (hp==0){
      __syncthreads();                       // heads done reading half 0
      if (half==1){
        #pragma unroll
        for (int pp=0;pp<16;pp++){
          double hv=acc[pp]+bc; if (hv<0.0) hv=0.0;
          hshp[c*17+pp]=hv;
        }
      }
      __syncthreads();                       // half 1 ready
    }
  }
}

// ============================================================================
// Kernel C (k_mid2, 1024 thr): [0,4): fg/bg sampling. [4,14): top-k with
// on-the-fly box decode. lvl0 topk blocks also init keepbuf to all-ones.
// ============================================================================
__global__ __launch_bounds__(1024) void k_mid2(const uint32_t* __restrict__ ub,
    const int* __restrict__ prelab, const int* __restrict__ counts,
    int* __restrict__ labels,
    const double* __restrict__ logits, const double* __restrict__ dpred,
    double* __restrict__ allS, double* __restrict__ allB,
    unsigned long long* __restrict__ keepbuf)
{
  __shared__ __align__(16) char buf[49152];
  __shared__ int hist[256];
  __shared__ int sI0, sI1;
  __shared__ int cnt;
  const int tid=threadIdx.x;

  if (blockIdx.x < 4){
    uint32_t* skey=(uint32_t*)buf; int* sidx=(int*)(buf+16384);
    const int img=blockIdx.x>>1, cls=blockIdx.x&1;
    const int cfg=counts[img*2+0], cbg=counts[img*2+1];
    const int num_fg=cfg<128?cfg:128;
    const int cap_bg=256-num_fg;
    const int num=cls?(cbg<cap_bg?cbg:cap_bg):num_fg;
    if (num<=0) return;
    const int want=cls?0:1;
    const int sel=want;
    const uint32_t* u=ub+(size_t)(img*2+cls)*R_TOT;
    const int* pl=prelab+(size_t)img*R_TOT;
    int* lab=labels+(size_t)img*R_TOT;

    for (int b=tid;b<256;b+=1024) hist[b]=0;
    if (tid==0) cnt=0;
    __syncthreads();
    #pragma unroll 4
    for (int r=tid;r<R_TOT;r+=1024){
      int plr = pl[r];
      uint32_t key = u[r]>>9;
      if (plr==want) atomicAdd(&hist[key>>15],1);
    }
    __syncthreads();
    hist_select(hist, num, tid, &sI0, &sI1);
    const uint32_t bsel=(uint32_t)sI0; const int kneed=sI1;
    #pragma unroll 4
    for (int r=tid;r<R_TOT;r+=1024){
      int plr = pl[r];
      uint32_t key = u[r]>>9;
      if (plr==want){
        uint32_t t8=key>>15;
        if (t8<bsel) lab[r]=sel;
        else if (t8==bsel){ int p=atomicAdd(&cnt,1); if (p<4096){ skey[p]=key; sidx[p]=r; } }
      }
    }
    __syncthreads();
    int n=cnt<4096?cnt:4096;
    for (int i=tid;i<4096;i+=1024) if (i>=n){ skey[i]=0xFFFFFFFFu; sidx[i]=0x7FFFFFFF; }
    bitonic_asc_u(skey,sidx,4096,tid,1024);
    int take = kneed<n?kneed:n;
    for (int i=tid;i<take;i+=1024) lab[sidx[i]]=sel;
  } else {
    double* sv=(double*)buf; int* si=(int*)(buf+32768);
    const int Rl[5]   ={98304,24576,6144,1536,384};
    const int kl[5]   ={2000,2000,2000,1536,384};
    const int lbase[5]={0,98304,122880,129024,130560};
    const int loff[5] ={0,2000,4000,6000,7536};
    const int bb=blockIdx.x-4;
    const int lvl=bb%5, img=bb/5;
    if (lvl==0 && tid<124) keepbuf[img*124+tid]=~0ull;   // init for k_post
    const int Rn=Rl[lvl], K=kl[lvl];
    const double* lg=logits+(size_t)img*R_TOT+lbase[lvl];

    unsigned long long chosen=0; int kneed=K;
    for (int ps=7; ps>=6; --ps){
      int shift=ps*8;
      for (int b=tid;b<256;b+=1024) hist[b]=0;
      __syncthreads();
      #pragma unroll 4
      for (int r=tid;r<Rn;r+=1024){
        unsigned long long ik=~mono64(lg[r]);
        bool okp=(ps==7)||((ik>>(shift+8))==(chosen>>(shift+8)));
        if (okp) atomicAdd(&hist[(int)((ik>>shift)&255)],1);
      }
      __syncthreads();
      hist_select(hist, kneed, tid, &sI0, &sI1);
      chosen = chosen | ((unsigned long long)sI0<<shift);
      kneed  = sI1;
      __syncthreads();
    }
    const unsigned long long lim = chosen | 0xFFFFFFFFFFFFull;
    if (tid==0) cnt=0;
    __syncthreads();
    #pragma unroll 4
    for (int r=tid;r<Rn;r+=1024){
      unsigned long long ik=~mono64(lg[r]);
      if (ik<=lim){ int p=atomicAdd(&cnt,1); if (p<4096){ sv[p]=lg[r]; si[p]=r; } }
    }
    __syncthreads();
    int n=cnt<4096?cnt:4096;
    for (int i=tid;i<4096;i+=1024) if (i>=n){ sv[i]=-HUGE_VAL; si[i]=0x7FFFFFFF; }
    bitonic_desc(sv,si,4096,tid,1024);
    for (int j=tid;j<K;j+=1024){
      double v=sv[j]; int r=si[j];
      size_t slot=(size_t)img*TOTK+loff[lvl]+j;
      allS[slot]=v;
      int ridx=lbase[lvl]+r;
      double bx[4];
      decode_box(ridx, dpred+((size_t)img*R_TOT+ridx)*4, bx);
      allB[slot*4+0]=bx[0]; allB[slot*4+1]=bx[1]; allB[slot*4+2]=bx[2]; allB[slot*4+3]=bx[3];
    }
  }
}

// ============================================================================
// Kernel D (k_mid3): [0,1980): NMS mask, 8 rows/block, boxes in LDS.
// SYMMETRIC mask now (j!=i): lower triangle is the exact transpose (iou_cf
// is bitwise-symmetric: fmax/fmin/add/mul commutative). Upper bits feed the
// cross-group suppression; lower bits feed the in-group fixed point.
//                    [1980,2236): loss partials.
// ============================================================================
__global__ __launch_bounds__(256) void k_mid3(const double* __restrict__ allB,
    unsigned long long* __restrict__ msk,
    const double* __restrict__ logits, const double* __restrict__ dpred,
    const float* __restrict__ gt, const int* __restrict__ labels,
    const int* __restrict__ matched, double* __restrict__ part)
{
  const int bx=blockIdx.x, tid=threadIdx.x;
  if (bx < 1980){
    __shared__ double Bsh[8000];
    const int kl[5]  ={2000,2000,2000,1536,384};
    const int loff[5]={0,2000,4000,6000,7536};
    const int rbc[6] ={0,250,500,750,942,990};
    const int img = bx/990; int t = bx - img*990;
    int lvl=0; while (lvl<4 && t>=rbc[lvl+1]) lvl++;
    const int i0=(t-rbc[lvl])*8;
    const int K=kl[lvl]; const int nw=(K+63)>>6;
    const double* B=allB+(size_t)(img*TOTK+loff[lvl])*4;
    for (int q=tid;q<K*4;q+=256) Bsh[q]=B[q];
    __syncthreads();
    const int wv=tid>>6, lane=tid&63;
    for (int rr=0;rr<8;rr++){
      int i=i0+rr;
      if (i>=K) break;
      const double bi0=Bsh[i*4],bi1=Bsh[i*4+1],bi2=Bsh[i*4+2],bi3=Bsh[i*4+3];
      const double areai=(bi2-bi0)*(bi3-bi1);
      for (int w=wv;w<nw;w+=4){
        int j=w*64+lane;
        bool pred=false;
        if (j<K && j!=i){
          double a0=Bsh[j*4],a1=Bsh[j*4+1],a2=Bsh[j*4+2],a3=Bsh[j*4+3];
          double lt0=fmax(bi0,a0), lt1=fmax(bi1,a1);
          double rb0=fmin(bi2,a2), rb1=fmin(bi3,a3);
          double ww=rb0-lt0; if (ww<0.0) ww=0.0;
          double hh=rb1-lt1; if (hh<0.0) hh=0.0;
          double inter=ww*hh;
          double uni=areai+(a2-a0)*(a3-a1)-inter;
          double iou=inter>0.0?inter/uni:0.0;
          pred = iou>0.7;
        }
        unsigned long long m=__ballot(pred);
        if (lane==0) msk[((size_t)img*TOTK+loff[lvl]+i)*32+w]=m;
      }
    }
  } else {
    const int bid2=bx-1980;
    double cls=0.0, loc=0.0;
    for (int idx=bid2*256+tid; idx<2*R_TOT; idx+=256*256){
      int l=labels[idx];
      if (l<0) continue;
      double x=logits[idx];
      double fgv=(l==1)?1.0:0.0;
      cls += fmax(x,0.0)-x*fgv+log1p(exp(-fabs(x)));
      if (l==1){
        int img=idx/R_TOT, r=idx-img*R_TOT;
        double a[4]; anchor_of(r,a);
        int m=matched[idx];
        const float* g=gt+img*128+m*4;
        double sw=a[2]-a[0], sh=a[3]-a[1];
        double scx=a[0]+0.5*sw, scy=a[1]+0.5*sh;
        double tw=(double)g[2]-(double)g[0], th=(double)g[3]-(double)g[1];
        double tcx=(double)g[0]+0.5*tw, tcy=(double)g[1]+0.5*th;
        double d0=(tcx-scx)/sw, d1=(tcy-scy)/sh;
        double d2=log(tw/sw), d3=log(th/sh);
        const double* dp=dpred+(size_t)idx*4;
        loc += fabs(dp[0]-d0)+fabs(dp[1]-d1)+fabs(dp[2]-d2)+fabs(dp[3]-d3);
      }
    }
    __shared__ double sc[256], sl[256];
    sc[tid]=cls; sl[tid]=loc; __syncthreads();
    for (int s=128;s>0;s>>=1){
      if (tid<s){ sc[tid]+=sc[tid+s]; sl[tid]+=sl[tid+s]; }
      __syncthreads();
    }
    if (tid==0){ part[bid2*2]=sc[0]; part[bid2*2+1]=sl[0]; }
  }
}

// ============================================================================
// Kernel E (k_post, 13 blocks x 256 thr — co-resident => spin-flags safe):
//  [0,10): ballot fixed-point greedy NMS scan -> keepbuf -> flags++.
//  [10,12): per-image top-1000 after spin flags[img]==5.
//  [12]:   loss final reduce.
// ============================================================================
__global__ __launch_bounds__(256) void k_post(const double* __restrict__ allB,
    const double* __restrict__ allS, const unsigned long long* __restrict__ msk,
    const double* __restrict__ part, int* __restrict__ flags,
    unsigned long long* __restrict__ keepbuf, float* __restrict__ out)
{
  const int tid=threadIdx.x, bx=blockIdx.x;
  const int kl[5]  ={2000,2000,2000,1536,384};
  const int loff[5]={0,2000,4000,6000,7536};

  if (bx < 10){
    // ---------------- ballot fixed-point greedy NMS scan ----------------
    if (tid >= 64) return;
    const int lvl=bx%5, img=bx/5;
    const int K=kl[lvl], off=loff[lvl], nw=(K+63)>>6;
    const int lane=tid;
    const double* B=allB+(size_t)(img*TOTK+off)*4;
    const unsigned long long* M=msk+((size_t)img*TOTK+off)*32;
    unsigned long long keepw=0ull;               // lane's 64-box keep word
    if (lane<nw){
      for (int b=0;b<64;b++){
        int j=lane*64+b;
        if (j<K){
          double x1=B[(size_t)j*4],y1=B[(size_t)j*4+1],x2=B[(size_t)j*4+2],y2=B[(size_t)j*4+3];
          if ((x2-x1)>0.0 && (y2-y1)>0.0) keepw|=(1ull<<b);
        }
      }
    }
    // Per 64-row group w: lane L = in-group box L.
    //  m_lo = own row's in-group word, bits < L  ("who below me suppresses me")
    //  kmask = ballot(valid && (m_lo & kmask)==0)  -> unique fixed point
    //        = greedy kept set (prefix-induction proof). No loads/shfl in chain.
    for (int w=0; w<nw; w++){
      unsigned long long vw = __shfl(keepw, w);  // group's current valid bits
      int row = w*64 + lane;
      unsigned long long mrow = (row<K) ? M[(size_t)row*32+w] : 0ull;
      unsigned long long m_lo = lane ? (mrow & ((1ull<<lane)-1ull)) : 0ull;
      const bool validL = (vw>>lane)&1ull;
      unsigned long long kmask = vw;
      while (true){
        bool s = validL && ((m_lo & kmask)==0ull);
        unsigned long long nk = __ballot(s);
        if (nk==kmask) break;
        kmask = nk;
      }
      if (lane==w) keepw = kmask;
      if (lane>w && lane<nw){                    // bulk cross-group suppression
        unsigned long long sup=0ull;
        for (int b=0;b<64;b++){
          if ((kmask>>b)&1ull) sup |= M[(size_t)(w*64+b)*32+lane];
        }
        keepw &= ~sup;
      }
    }
    // publish suppression to keepbuf (global bit positions off+lane*64..)
    if (lane<nw){
      int nvalid = K - lane*64; if (nvalid>64) nvalid=64;
      unsigned long long vm = (nvalid>=64) ? ~0ull : ((1ull<<nvalid)-1ull);
      unsigned long long cbits = (~keepw) & vm;  // bits to clear
      int gbase = off + lane*64;
      int w0 = gbase>>6, sh = gbase&63;
      unsigned long long* kb = keepbuf + (size_t)img*124;
      if (sh==0){
        if (cbits) atomicAnd(&kb[w0], ~cbits);
      } else {
        unsigned long long lo = cbits << sh;
        unsigned long long hi = cbits >> (64-sh);
        if (lo) atomicAnd(&kb[w0],   ~lo);
        if (hi) atomicAnd(&kb[w0+1], ~hi);
      }
    }
    __threadfence();
    if (tid==0) atomicAdd(&flags[img],1);
    return;
  }

  if (bx < 12){
    // ---------------- per-image top-1000 (256 threads) ----------------
    const int img=bx-10;
    if (tid==0){
      while (atomicAdd(&flags[img],0) < 5) __builtin_amdgcn_s_sleep(8);
    }
    __syncthreads();
    __threadfence();
    __shared__ unsigned long long kbl[124];
    if (tid<124) kbl[tid]=atomicAdd(&keepbuf[(size_t)img*124+tid],0ull);
    __syncthreads();
    const double* sarr=allS+(size_t)img*TOTK;
    __shared__ int hist[256];
    __shared__ int sI0, sI1;
    __shared__ double sv[4096]; __shared__ int si[4096]; __shared__ int cnt;

    unsigned long long chosen=0; int kneed=1000;
    for (int ps=7; ps>=6; --ps){
      int shift=ps*8;
      hist[tid]=0;
      __syncthreads();
      for (int r=tid;r<TOTK;r+=256){
        bool kept = (kbl[r>>6]>>(r&63))&1ull;
        double val = kept ? sarr[r] : -HUGE_VAL;
        unsigned long long ik=~mono64(val);
        bool okp=(ps==7)||((ik>>(shift+8))==(chosen>>(shift+8)));
        if (okp) atomicAdd(&hist[(int)((ik>>shift)&255)],1);
      }
      __syncthreads();
      hist_select(hist, kneed, tid, &sI0, &sI1);
      chosen = chosen | ((unsigned long long)sI0<<shift);
      kneed  = sI1;
      __syncthreads();
    }
    const unsigned long long lim = chosen | 0xFFFFFFFFFFFFull;
    if (tid==0) cnt=0;
    __syncthreads();
    for (int r=tid;r<TOTK;r+=256){
      bool kept = (kbl[r>>6]>>(r&63))&1ull;
      double val = kept ? sarr[r] : -HUGE_VAL;
      unsigned long long ik=~mono64(val);
      if (ik<=lim){ int p=atomicAdd(&cnt,1); if (p<4096){ sv[p]=val; si[p]=r; } }
    }
    __syncthreads();
    int n=cnt<4096?cnt:4096;
    for (int i=tid;i<4096;i+=256) if (i>=n){ sv[i]=-HUGE_VAL; si[i]=0x7FFFFFFF; }
    bitonic_desc(sv,si,4096,tid,256);
    for (int j=tid;j<1000;j+=256){
      out[8000+img*1000+j]=(float)sv[j];
      int idx=si[j];
      const double* b=allB+((size_t)img*TOTK+idx)*4;
      float* ob=out+((size_t)img*1000+j)*4;
      ob[0]=(float)b[0]; ob[1]=(float)b[1]; ob[2]=(float)b[2]; ob[3]=(float)b[3];
    }
    return;
  }

  // ---------------- loss final reduce ----------------
  __shared__ double sc[256], sl[256];
  sc[tid]=part[tid*2]; sl[tid]=part[tid*2+1];
  __syncthreads();
  for (int s=128;s>0;s>>=1){
    if (tid<s){ sc[tid]+=sc[tid+s]; sl[tid]+=sl[tid+s]; }
    __syncthreads();
  }
  if (tid==0){ out[10000]=(float)(sc[0]/512.0); out[10001]=(float)(sl[0]/512.0); }
}

// ============================================================================
// Host launcher
// ============================================================================
extern "C" void kernel_launch(void* const* d_in, const int* in_sizes, int n_in,
                              void* d_out, int out_size, void* d_ws, size_t ws_size,
                              hipStream_t stream)
{
  (void)in_sizes; (void)n_in; (void)out_size;
  const float* feats[5];
  for (int i=0;i<5;i++) feats[i]=(const float*)d_in[i];
  const float* gt =(const float*)d_in[5];
  const float* cw =(const float*)d_in[6];
  const float* cb =(const float*)d_in[7];
  const float* ow =(const float*)d_in[8];
  const float* ob =(const float*)d_in[9];
  const float* dwt=(const float*)d_in[10];
  const float* dbt=(const float*)d_in[11];
  float* out=(float*)d_out;

  char* p=(char*)d_ws;
  auto carve=[&](size_t nbytes)->char*{ char* q=p; p += (nbytes+255)&~(size_t)255; return q; };
  double* logits =(double*)carve(2ull*R_TOT*8);
  double* dpred  =(double*)carve(2ull*R_TOT*4*8);
  float* cwTf    =(float*)carve(147456ull*4);
  uint32_t* ub   =(uint32_t*)carve(4ull*R_TOT*4);
  int* prelab    =(int*)carve(2ull*R_TOT*4);
  int* matched   =(int*)carve(2ull*R_TOT*4);
  int* labels    =(int*)carve(2ull*R_TOT*4);
  unsigned long long* highest=(unsigned long long*)carve(2*32*8);   // +0:   512B
  int* counts    =(int*)carve(256);                                  // +512: 256B
  int* flags     =(int*)carve(256);                                  // +768: 256B
  double* allS   =(double*)carve(2ull*TOTK*8);
  double* allB   =(double*)carve(2ull*TOTK*4*8);
  unsigned long long* msk=(unsigned long long*)carve(2ull*TOTK*32*8);
  double* part   =(double*)carve(256*2*8);
  unsigned long long* keepbuf=(unsigned long long*)carve(2*124*8);   // init in k_mid2
  if ((size_t)(p-(char*)d_ws) > ws_size) return;

  hipMemsetAsync(highest, 0, 1024, stream);  // highest + counts + flags (contiguous)

  uint32_t a0,b0,a1,b1;
  threefry(0u,42u,0u,2u,&a0,&b0);
  threefry(0u,42u,1u,3u,&a1,&b1);
  uint32_t kf00,kf01,kb00,kb01,kf10,kf11,kb10,kb11;
  { uint32_t c0,d0,c1,d1;
    threefry(a0,a1,0u,2u,&c0,&d0); threefry(a0,a1,1u,3u,&c1,&d1);
    kf00=c0; kf01=c1; kb00=d0; kb01=d1;
    threefry(b0,b1,0u,2u,&c0,&d0); threefry(b0,b1,1u,3u,&c1,&d1);
    kf10=c0; kf11=c1; kb10=d0; kb11=d1; }

  k_pre<<<704, 256, 0, stream>>>(cw, cwTf, gt, highest);
  k_conv_label<<<4775, 256, 0, stream>>>(feats[0],feats[1],feats[2],feats[3],feats[4],
      cwTf,cb,ow,ob,dwt,dbt, logits, dpred,
      gt, highest, prelab, matched, labels, counts,
      ub, kf00,kf01,kb00,kb01,kf10,kf11,kb10,kb11);
  k_mid2<<<14, 1024, 0, stream>>>(ub, prelab, counts, labels, logits, dpred, allS, allB, keepbuf);
  k_mid3<<<2236, 256, 0, stream>>>(allB, msk, logits, dpred, gt, labels, matched, part);
  k_post<<<13, 256, 0, stream>>>(allB, allS, msk, part, flags, keepbuf, out);
}

// Round 16
// 1252.038 us; speedup vs baseline: 1.6688x; 1.1219x over previous
//
#include <hip/hip_runtime.h>
#include <stdint.h>
#include <math.h>

// ============================================================================
// RPN forward (detectron2-style) on MI355X — fp64 ordering-exact pipeline.
// R16: post-tail fused into the wide mid3 dispatch. The serial NMS scan +
// top-1000 ran on a near-idle GPU (13 blocks -> clock throttle ~5x; R11-R15
// all ~530-590us regardless of scan algorithm). Now one 575-block kernel:
// [0,10) scans (spin on per-level mask counters), [10,12) top-1000 @1024thr
// (spin on scan counter), [12] loss-final (spin on loss counter),
// [13,511) NMS masks (32 rows/blk), [511,575) loss partials. Mask+loss work
// keeps clocks high while the serial parts run. 6 -> 4 launches.
// ============================================================================

#define R_TOT   130944
#define HALF_R  65472
#define TOTK    7920
#define SCALE_CLAMP 4.135166556742356  // log(1000/16)

// ---------------- threefry2x32-20 (JAX-compatible) ----------------
__host__ __device__ inline void threefry(uint32_t k0, uint32_t k1,
                                         uint32_t x0, uint32_t x1,
                                         uint32_t* o0, uint32_t* o1)
{
  uint32_t ks[3]; ks[0]=k0; ks[1]=k1; ks[2]=k0^k1^0x1BD11BDAu;
  x0 += ks[0]; x1 += ks[1];
  const uint32_t rot0[4] = {13u,15u,26u,6u};
  const uint32_t rot1[4] = {17u,29u,16u,24u};
  for (int i = 0; i < 5; i++){
    const uint32_t* rot = (i & 1) ? rot1 : rot0;
    for (int q = 0; q < 4; q++){
      x0 += x1;
      x1 = (x1 << rot[q]) | (x1 >> (32u - rot[q]));
      x1 ^= x0;
    }
    x0 += ks[(i+1)%3];
    x1 += ks[(i+2)%3] + (uint32_t)(i+1);
  }
  *o0 = x0; *o1 = x1;
}

// ---------------- helpers ----------------
__device__ inline unsigned long long mono64(double v){
  unsigned long long b = (unsigned long long)__double_as_longlong(v);
  return (b & 0x8000000000000000ull) ? ~b : (b | 0x8000000000000000ull);
}

__device__ __forceinline__ double iou_cf(double g0,double g1,double g2,double g3,
                                         double a0,double a1,double a2,double a3){
  #pragma clang fp contract(off)
  double lt0 = fmax(g0,a0), lt1 = fmax(g1,a1);
  double rb0 = fmin(g2,a2), rb1 = fmin(g3,a3);
  double w = rb0-lt0; if (w<0.0) w=0.0;
  double h = rb1-lt1; if (h<0.0) h=0.0;
  double inter = w*h;
  double aa = (g2-g0)*(g3-g1);
  double ab = (a2-a0)*(a3-a1);
  double uni = aa+ab-inter;
  return inter>0.0 ? inter/uni : 0.0;
}

__device__ __forceinline__ void anchor_of(int r, double* o){
  #pragma clang fp contract(off)
  const int    base[5]={0,98304,122880,129024,130560};
  const int    Wl[5]  ={256,128,64,32,16};
  const double strd[5]={4.0,8.0,16.0,32.0,64.0};
  const double size[5]={32.0,64.0,128.0,256.0,512.0};
  const double ratio[3]={0.5,1.0,2.0};
  int l=0; while (l<4 && r>=base[l+1]) l++;
  int rr=r-base[l]; int pix=rr/3; int a=rr-pix*3;
  int x=pix%Wl[l], y=pix/Wl[l];
  double w=sqrt(size[l]*size[l]/ratio[a]);
  double h=w*ratio[a];
  double sx=(double)x*strd[l], sy=(double)y*strd[l];
  o[0]=sx-0.5*w; o[1]=sy-0.5*h; o[2]=sx+0.5*w; o[3]=sy+0.5*h;
}

// apply_deltas + clip
__device__ __forceinline__ void decode_box(int ridx, const double* __restrict__ d,
                                           double* __restrict__ o){
  double a[4]; anchor_of(ridx,a);
  double w=a[2]-a[0], h=a[3]-a[1];
  double cx=a[0]+0.5*w, cy=a[1]+0.5*h;
  double dw=fmin(d[2],SCALE_CLAMP), dh=fmin(d[3],SCALE_CLAMP);
  double pcx=d[0]*w+cx, pcy=d[1]*h+cy;
  double pw=exp(dw)*w, ph=exp(dh)*h;
  double x1=pcx-0.5*pw, y1=pcy-0.5*ph;
  double x2=pcx+0.5*pw, y2=pcy+0.5*ph;
  o[0]=fmin(fmax(x1,0.0),1024.0); o[1]=fmin(fmax(y1,0.0),512.0);
  o[2]=fmin(fmax(x2,0.0),1024.0); o[3]=fmin(fmax(y2,0.0),512.0);
}

__device__ inline void bitonic_desc(double* sv, int* si, int M, int tid, int nthr){
  for (int k=2;k<=M;k<<=1)
    for (int j=k>>1;j>0;j>>=1){
      __syncthreads();
      for (int i=tid;i<M;i+=nthr){
        int ixj=i^j;
        if (ixj>i){
          double va=sv[i], vb=sv[ixj]; int ia=si[i], ib=si[ixj];
          bool before = (va>vb) || (va==vb && ia<ib);
          bool up = ((i&k)==0);
          if (up ? !before : before){ sv[i]=vb; sv[ixj]=va; si[i]=ib; si[ixj]=ia; }
        }
      }
    }
  __syncthreads();
}

__device__ inline void bitonic_asc_u(uint32_t* sk, int* si, int M, int tid, int nthr){
  for (int k=2;k<=M;k<<=1)
    for (int j=k>>1;j>0;j>>=1){
      __syncthreads();
      for (int i=tid;i<M;i+=nthr){
        int ixj=i^j;
        if (ixj>i){
          uint32_t ka=sk[i], kb=sk[ixj]; int ia=si[i], ib=si[ixj];
          bool before = (ka<kb) || (ka==kb && ia<ib);
          bool up = ((i&k)==0);
          if (up ? !before : before){ sk[i]=kb; sk[ixj]=ka; si[i]=ib; si[ixj]=ia; }
        }
      }
    }
  __syncthreads();
}

// Parallel select over hist[256] (in-place inclusive scan). blockDim >= 256.
__device__ inline void hist_select(int* hist, int kneed, int tid,
                                   int* shb, int* shk){
  for (int off=1; off<256; off<<=1){
    int v=0;
    if (tid<256 && tid>=off) v=hist[tid-off];
    __syncthreads();
    if (tid<256) hist[tid]+=v;
    __syncthreads();
  }
  if (tid<256){
    int prev = tid ? hist[tid-1] : 0;
    if (prev < kneed && kneed <= hist[tid]){ *shb=tid; *shk=kneed-prev; }
    if (tid==255 && kneed > hist[255]){ *shb=255; *shk=kneed-hist[254]; }
  }
  __syncthreads();
}

// ============================================================================
// Kernel A (k_pre): [0,576): weight permute cw->cwTf[ci][k9][cc] f32.
//                   [576,704): per-gt max IoU (gtmax).
// ============================================================================
__global__ __launch_bounds__(256) void k_pre(const float* __restrict__ cw,
    float* __restrict__ cwTf, const float* __restrict__ gt,
    unsigned long long* __restrict__ highest)
{
  const int bx=blockIdx.x, tid=threadIdx.x;
  if (bx < 576){
    int o = bx*256 + tid;
    if (o >= 147456) return;
    int cc = o & 127; int t = o >> 7;
    int k9 = t % 9;  int ci = t / 9;
    cwTf[(size_t)(ci*9+k9)*128 + cc] = cw[(size_t)cc*1152 + ci*9 + k9];
  } else {
    __shared__ double gts[128];
    __shared__ unsigned long long lmax[32];
    const int gb=bx-576;
    const int img=gb>>6, b=gb&63;
    if (tid<128) gts[tid]=(double)gt[img*128+tid];
    if (tid<32) lmax[tid]=0ull;
    __syncthreads();
    double gm[32];
    #pragma unroll
    for (int g=0;g<32;g++) gm[g]=0.0;
    for (int r=b*256+tid; r<R_TOT; r+=64*256){
      double a[4]; anchor_of(r,a);
      #pragma unroll
      for (int g=0;g<32;g++){
        double v=iou_cf(gts[g*4],gts[g*4+1],gts[g*4+2],gts[g*4+3],a[0],a[1],a[2],a[3]);
        gm[g]=fmax(gm[g],v);
      }
    }
    #pragma unroll
    for (int g=0;g<32;g++){
      double v=gm[g];
      #pragma unroll
      for (int off=1; off<64; off<<=1) v=fmax(v,__shfl_xor(v,off));
      if ((tid&63)==0) atomicMax(&lmax[g],(unsigned long long)__double_as_longlong(v));
    }
    __syncthreads();
    if (tid<32) atomicMax(&highest[img*32+tid], lmax[tid]);
  }
}

// ============================================================================
// Kernel B (k_conv_label): [0,2728): conv+heads. [2728,3752): labels.
// [3752,4775): threefry ubits.
// ============================================================================
#define CTH 4
#define CTW 8

__global__ __launch_bounds__(256,3) void k_conv_label(
    const float* __restrict__ f2, const float* __restrict__ f3,
    const float* __restrict__ f4, const float* __restrict__ f5,
    const float* __restrict__ f6,
    const float* __restrict__ cwTf, const float* __restrict__ cb,
    const float* __restrict__ ow, const float* __restrict__ ob,
    const float* __restrict__ dwt, const float* __restrict__ dbt,
    double* __restrict__ logits, double* __restrict__ dpred,
    const float* __restrict__ gt, const unsigned long long* __restrict__ highest,
    int* __restrict__ prelab, int* __restrict__ matched,
    int* __restrict__ labels, int* __restrict__ counts,
    uint32_t* __restrict__ ub,
    uint32_t kf00,uint32_t kf01,uint32_t kb00,uint32_t kb01,
    uint32_t kf10,uint32_t kf11,uint32_t kb10,uint32_t kb11)
{
  __shared__ double fshd[4][6][12];
  __shared__ __align__(16) char ush[18432];   // wshF [4][9][128] f32 / hshp [128][17] dbl / label arrays
  float*  wshF = (float*)ush;
  double* hshp = (double*)ush;
  __shared__ float hw[15*128];
  __shared__ float hb[15];

  const int tid=threadIdx.x;
  const int vbid = blockIdx.x;

  if (vbid >= 3752){
    // ------------------- ubits path -------------------
    int j = (vbid-3752)*256 + tid;
    if (j >= 2*R_TOT) return;
    int slot = j / HALF_R; int t = j - slot*HALF_R;
    uint32_t k0,k1;
    if      (slot==0){k0=kf00;k1=kf01;}
    else if (slot==1){k0=kb00;k1=kb01;}
    else if (slot==2){k0=kf10;k1=kf11;}
    else             {k0=kb10;k1=kb11;}
    uint32_t o0,o1;
    threefry(k0,k1,(uint32_t)t,(uint32_t)(t+HALF_R),&o0,&o1);
    ub[(size_t)slot*R_TOT+t]=o0;
    ub[(size_t)slot*R_TOT+t+HALF_R]=o1;
    return;
  }

  if (vbid >= 2728){
    // ------------------- label path -------------------
    double* gts=(double*)ush;                        // [128]
    double* hg =(double*)(ush+1024);                 // [32]
    int* wfg=(int*)(ush+1280); int* wbg=(int*)(ush+1296);
    const int lb=vbid-2728;
    const int img=lb>>9, blk=lb&511;
    if (tid<128) gts[tid]=(double)gt[img*128+tid];
    if (tid<32)  hg[tid]=__longlong_as_double((long long)highest[img*32+tid]);
    __syncthreads();
    int r=blk*256+tid;
    const bool ok=(r<R_TOT);
    int lab=-1, bi=0;
    if (ok){
      double a[4]; anchor_of(r,a);
      double best=-1.0; bool lq=false;
      #pragma unroll
      for (int g=0;g<32;g++){
        double v=iou_cf(gts[g*4],gts[g*4+1],gts[g*4+2],gts[g*4+3],a[0],a[1],a[2],a[3]);
        if (v>best){ best=v; bi=g; }
        if (hg[g]>0.0 && v==hg[g]) lq=true;
      }
      lab = lq ? 1 : (best>=0.7 ? 1 : (best>=0.3 ? -1 : 0));
      prelab [(size_t)img*R_TOT+r]=lab;
      matched[(size_t)img*R_TOT+r]=bi;
      labels [(size_t)img*R_TOT+r]=-1;
    }
    unsigned long long bf=__ballot(ok && lab==1);
    unsigned long long bb=__ballot(ok && lab==0);
    const int wid=tid>>6, lane=tid&63;
    if (lane==0){ wfg[wid]=__popcll(bf); wbg[wid]=__popcll(bb); }
    __syncthreads();
    if (tid==0){
      int fcnt=wfg[0]+wfg[1]+wfg[2]+wfg[3];
      int bcnt=wbg[0]+wbg[1]+wbg[2]+wbg[3];
      if (fcnt) atomicAdd(&counts[img*2+0],fcnt);
      if (bcnt) atomicAdd(&counts[img*2+1],bcnt);
    }
    return;
  }

  // ------------------- conv path -------------------
  const int cumt[6]={0,2048,2560,2688,2720,2728};
  const int Hs[5]={128,64,32,16,8}, Wl[5]={256,128,64,32,16};
  const int rbs[5]={0,98304,122880,129024,130560};
  const int lgx[5]={5,4,3,2,1};

  int bid=vbid;
  int lvl=0;
  while (lvl<4 && bid>=cumt[lvl+1]) lvl++;
  int t=bid-cumt[lvl];
  const int img=t&1; const int tt=t>>1;
  const int H=Hs[lvl], W=Wl[lvl], rbase=rbs[lvl];
  const int tx=tt&((1<<lgx[lvl])-1), ty=tt>>lgx[lvl];
  const int x0=tx*CTW, y0=ty*CTH;
  const float* f = lvl==0?f2: lvl==1?f3: lvl==2?f4: lvl==3?f5: f6;

  for (int i=tid;i<15*128;i+=256){
    int o=i>>7, c=i&127;
    hw[i]=(o<3)?ow[o*128+c]:dwt[(o-3)*128+c];
  }
  if (tid<15) hb[tid]=(tid<3)?ob[tid]:dbt[tid-3];

  const int c=tid&127, half=tid>>7;
  double acc[16];
  #pragma unroll
  for (int i=0;i<16;i++) acc[i]=0.0;

  const float* fimg = f + (size_t)img*128*H*W;

  const bool fin_act = (tid < 240);
  int ci_f=0,dy_f=0,dx_f=0; bool fin_valid=false;
  const float* fptr=fimg;
  if (fin_act){
    ci_f=tid/60; int rem=tid-ci_f*60; dy_f=rem/10; dx_f=rem-dy_f*10;
    int y=y0-1+dy_f, x=x0-1+dx_f;
    fin_valid = (y>=0&&y<H&&x>=0&&x<W);
    fptr = fimg + (size_t)ci_f*H*W + (fin_valid ? ((size_t)y*W+x) : 0);
  }
  const size_t fstep=(size_t)4*H*W;
  const float2* wsrc=(const float2*)cwTf;

  float fin_pf=0.f; float2 wpf[9];
  if (fin_act){ fin_pf = fin_valid ? *fptr : 0.f; fptr += fstep; }
  #pragma unroll
  for (int j2=0;j2<9;j2++) wpf[j2]=wsrc[tid+j2*256];

  for (int ci0=0; ci0<128; ci0+=4){
    __syncthreads();                         // prior compute done reading LDS
    if (fin_act) fshd[ci_f][dy_f][dx_f]=(double)fin_pf;
    { float2* wdst=(float2*)wshF;
      #pragma unroll
      for (int j2=0;j2<9;j2++) wdst[tid+j2*256]=wpf[j2]; }
    if (ci0+4<128){                          // issue next chunk (hidden by compute)
      if (fin_act){ fin_pf = fin_valid ? *fptr : 0.f; fptr += fstep; }
      const float2* wn = wsrc + (size_t)(ci0+4)*576;
      #pragma unroll
      for (int j2=0;j2<9;j2++) wpf[j2]=wn[tid+j2*256];
    }
    __syncthreads();                         // LDS ready
    #pragma unroll
    for (int ci=0;ci<4;ci++){
      double w9d[9];
      #pragma unroll
      for (int k=0;k<9;k++) w9d[k]=(double)wshF[(ci*9+k)*128 + c];
      #pragma unroll
      for (int irl=0;irl<4;irl++){
        int ir=half*2+irl;
        double rowb[10];
        #pragma unroll
        for (int q=0;q<10;q++) rowb[q]=fshd[ci][ir][q];
        #pragma unroll
        for (int orl=0;orl<2;orl++){
          int ky=irl-orl;
          if (ky<0||ky>2) continue;
          #pragma unroll
          for (int px=0;px<8;px++){
            double s=acc[orl*8+px];
            #pragma unroll
            for (int kx=0;kx<3;kx++) s += w9d[ky*3+kx]*rowb[px+kx];
            acc[orl*8+px]=s;
          }
        }
      }
    }
  }
  // ---- epilogue: two pixel halves (hshp [128][17], aliases wshF) ----
  double bc=(double)cb[c];
  __syncthreads();                           // wshF reads done
  if (half==0){
    #pragma unroll
    for (int pp=0;pp<16;pp++){
      double hv=acc[pp]+bc; if (hv<0.0) hv=0.0;
      hshp[c*17+pp]=hv;
    }
  }
  __syncthreads();
  for (int hp=0;hp<2;hp++){
    if (tid<240){
      int o=tid>>4, p=tid&15;
      double s=(double)hb[o];
      for (int c2=0;c2<128;c2++) s += (double)hw[o*128+c2]*hshp[c2*17+p];
      int pg=hp*16+p;
      int py=pg>>3, px=pg&7;
      int gy=y0+py, gx=x0+px;
      long long pix=(long long)gy*W+gx;
      size_t rb=(size_t)rbase+(size_t)pix*3;
      if (o<3) logits[(size_t)img*R_TOT+rb+o]=s;
      else { int a=(o-3)>>2, jj=(o-3)&3; dpred[((size_t)img*R_TOT+rb+a)*4+jj]=s; }
    }
    if (hp==0){
      __syncthreads();                       // heads done reading half 0
      if (half==1){
        #pragma unroll
        for (int pp=0;pp<16;pp++){
          double hv=acc[pp]+bc; if (hv<0.0) hv=0.0;
          hshp[c*17+pp]=hv;
        }
      }
      __syncthreads();                       // half 1 ready
    }
  }
}

// ============================================================================
// Kernel C (k_mid2, 1024 thr): [0,4): fg/bg sampling. [4,14): top-k with
// on-the-fly box decode. lvl0 topk blocks also init keepbuf to all-ones.
// ============================================================================
__global__ __launch_bounds__(1024) void k_mid2(const uint32_t* __restrict__ ub,
    const int* __restrict__ prelab, const int* __restrict__ counts,
    int* __restrict__ labels,
    const double* __restrict__ logits, const double* __restrict__ dpred,
    double* __restrict__ allS, double* __restrict__ allB,
    unsigned long long* __restrict__ keepbuf)
{
  __shared__ __align__(16) char buf[49152];
  __shared__ int hist[256];
  __shared__ int sI0, sI1;
  __shared__ int cnt;
  const int tid=threadIdx.x;

  if (blockIdx.x < 4){
    uint32_t* skey=(uint32_t*)buf; int* sidx=(int*)(buf+16384);
    const int img=blockIdx.x>>1, cls=blockIdx.x&1;
    const int cfg=counts[img*2+0], cbg=counts[img*2+1];
    const int num_fg=cfg<128?cfg:128;
    const int cap_bg=256-num_fg;
    const int num=cls?(cbg<cap_bg?cbg:cap_bg):num_fg;
    if (num<=0) return;
    const int want=cls?0:1;
    const int sel=want;
    const uint32_t* u=ub+(size_t)(img*2+cls)*R_TOT;
    const int* pl=prelab+(size_t)img*R_TOT;
    int* lab=labels+(size_t)img*R_TOT;

    for (int b=tid;b<256;b+=1024) hist[b]=0;
    if (tid==0) cnt=0;
    __syncthreads();
    #pragma unroll 4
    for (int r=tid;r<R_TOT;r+=1024){
      int plr = pl[r];
      uint32_t key = u[r]>>9;
      if (plr==want) atomicAdd(&hist[key>>15],1);
    }
    __syncthreads();
    hist_select(hist, num, tid, &sI0, &sI1);
    const uint32_t bsel=(uint32_t)sI0; const int kneed=sI1;
    #pragma unroll 4
    for (int r=tid;r<R_TOT;r+=1024){
      int plr = pl[r];
      uint32_t key = u[r]>>9;
      if (plr==want){
        uint32_t t8=key>>15;
        if (t8<bsel) lab[r]=sel;
        else if (t8==bsel){ int p=atomicAdd(&cnt,1); if (p<4096){ skey[p]=key; sidx[p]=r; } }
      }
    }
    __syncthreads();
    int n=cnt<4096?cnt:4096;
    for (int i=tid;i<4096;i+=1024) if (i>=n){ skey[i]=0xFFFFFFFFu; sidx[i]=0x7FFFFFFF; }
    bitonic_asc_u(skey,sidx,4096,tid,1024);
    int take = kneed<n?kneed:n;
    for (int i=tid;i<take;i+=1024) lab[sidx[i]]=sel;
  } else {
    double* sv=(double*)buf; int* si=(int*)(buf+32768);
    const int Rl[5]   ={98304,24576,6144,1536,384};
    const int kl[5]   ={2000,2000,2000,1536,384};
    const int lbase[5]={0,98304,122880,129024,130560};
    const int loff[5] ={0,2000,4000,6000,7536};
    const int bb=blockIdx.x-4;
    const int lvl=bb%5, img=bb/5;
    if (lvl==0 && tid<124) keepbuf[img*124+tid]=~0ull;   // init for the scan
    const int Rn=Rl[lvl], K=kl[lvl];
    const double* lg=logits+(size_t)img*R_TOT+lbase[lvl];

    unsigned long long chosen=0; int kneed=K;
    for (int ps=7; ps>=6; --ps){
      int shift=ps*8;
      for (int b=tid;b<256;b+=1024) hist[b]=0;
      __syncthreads();
      #pragma unroll 4
      for (int r=tid;r<Rn;r+=1024){
        unsigned long long ik=~mono64(lg[r]);
        bool okp=(ps==7)||((ik>>(shift+8))==(chosen>>(shift+8)));
        if (okp) atomicAdd(&hist[(int)((ik>>shift)&255)],1);
      }
      __syncthreads();
      hist_select(hist, kneed, tid, &sI0, &sI1);
      chosen = chosen | ((unsigned long long)sI0<<shift);
      kneed  = sI1;
      __syncthreads();
    }
    const unsigned long long lim = chosen | 0xFFFFFFFFFFFFull;
    if (tid==0) cnt=0;
    __syncthreads();
    #pragma unroll 4
    for (int r=tid;r<Rn;r+=1024){
      unsigned long long ik=~mono64(lg[r]);
      if (ik<=lim){ int p=atomicAdd(&cnt,1); if (p<4096){ sv[p]=lg[r]; si[p]=r; } }
    }
    __syncthreads();
    int n=cnt<4096?cnt:4096;
    for (int i=tid;i<4096;i+=1024) if (i>=n){ sv[i]=-HUGE_VAL; si[i]=0x7FFFFFFF; }
    bitonic_desc(sv,si,4096,tid,1024);
    for (int j=tid;j<K;j+=1024){
      double v=sv[j]; int r=si[j];
      size_t slot=(size_t)img*TOTK+loff[lvl]+j;
      allS[slot]=v;
      int ridx=lbase[lvl]+r;
      double bx[4];
      decode_box(ridx, dpred+((size_t)img*R_TOT+ridx)*4, bx);
      allB[slot*4+0]=bx[0]; allB[slot*4+1]=bx[1]; allB[slot*4+2]=bx[2]; allB[slot*4+3]=bx[3];
    }
  }
}

// ============================================================================
// Kernel D (k_mid3post, 575 blocks x 1024 thr):
//  [0,10): ballot fixed-point NMS scan per (img,lvl). Spins (wave 0) until
//          its level's mask blocks signal flags[img*5+lvl]==MBLK[lvl].
//  [10,12): per-image top-1000. Spins flags[10+img]==5 (scans done).
//  [12]:    loss final reduce. Spins flags[12]==64 (loss partials done).
//  [13,511): NMS mask, 32 rows/block, SYMMETRIC (j!=i), boxes in LDS.
//  [511,575): loss partials (64 blocks).
// The wide mask/loss blocks keep the GPU clocked while the serial parts run.
// ============================================================================
__global__ __launch_bounds__(1024) void k_mid3post(const double* __restrict__ allB,
    unsigned long long* __restrict__ msk,
    const double* __restrict__ logits, const double* __restrict__ dpred,
    const float* __restrict__ gt, const int* __restrict__ labels,
    const int* __restrict__ matched, double* __restrict__ part,
    const double* __restrict__ allS, int* __restrict__ flags,
    unsigned long long* __restrict__ keepbuf, float* __restrict__ out)
{
  __shared__ __align__(16) char ush[64000];
  const int tid=threadIdx.x, bx=blockIdx.x;
  const int kl[5]  ={2000,2000,2000,1536,384};
  const int loff[5]={0,2000,4000,6000,7536};
  const int MBLK[5]={63,63,63,48,12};

  if (bx < 10){
    // ------------- ballot fixed-point greedy NMS scan (wave 0 only) -------------
    if (tid >= 64) return;
    const int lvl=bx%5, img=bx/5;
    const int K=kl[lvl], off=loff[lvl], nw=(K+63)>>6;
    const int lane=tid;
    // spin until this (img,lvl)'s mask rows are published
    {
      const int target=MBLK[lvl];
      while (true){
        int v = (lane==0) ? atomicAdd(&flags[img*5+lvl],0) : 0;
        v = __shfl(v,0);
        if (v>=target) break;
        __builtin_amdgcn_s_sleep(8);
      }
      __threadfence();
    }
    const double* B=allB+(size_t)(img*TOTK+off)*4;
    const unsigned long long* M=msk+((size_t)img*TOTK+off)*32;
    unsigned long long keepw=0ull;
    if (lane<nw){
      for (int b=0;b<64;b++){
        int j=lane*64+b;
        if (j<K){
          double x1=B[(size_t)j*4],y1=B[(size_t)j*4+1],x2=B[(size_t)j*4+2],y2=B[(size_t)j*4+3];
          if ((x2-x1)>0.0 && (y2-y1)>0.0) keepw|=(1ull<<b);
        }
      }
    }
    for (int w=0; w<nw; w++){
      unsigned long long vw = __shfl(keepw, w);
      int row = w*64 + lane;
      unsigned long long mrow = (row<K) ? M[(size_t)row*32+w] : 0ull;
      unsigned long long m_lo = lane ? (mrow & ((1ull<<lane)-1ull)) : 0ull;
      const bool validL = (vw>>lane)&1ull;
      unsigned long long kmask = vw;
      while (true){
        bool s = validL && ((m_lo & kmask)==0ull);
        unsigned long long nk = __ballot(s);
        if (nk==kmask) break;
        kmask = nk;
      }
      if (lane==w) keepw = kmask;
      if (lane>w && lane<nw){
        unsigned long long sup=0ull;
        for (int b=0;b<64;b++){
          if ((kmask>>b)&1ull) sup |= M[(size_t)(w*64+b)*32+lane];
        }
        keepw &= ~sup;
      }
    }
    if (lane<nw){
      int nvalid = K - lane*64; if (nvalid>64) nvalid=64;
      unsigned long long vm = (nvalid>=64) ? ~0ull : ((1ull<<nvalid)-1ull);
      unsigned long long cbits = (~keepw) & vm;
      int gbase = off + lane*64;
      int w0 = gbase>>6, sh = gbase&63;
      unsigned long long* kb = keepbuf + (size_t)img*124;
      if (sh==0){
        if (cbits) atomicAnd(&kb[w0], ~cbits);
      } else {
        unsigned long long lo = cbits << sh;
        unsigned long long hi = cbits >> (64-sh);
        if (lo) atomicAnd(&kb[w0],   ~lo);
        if (hi) atomicAnd(&kb[w0+1], ~hi);
      }
    }
    __threadfence();
    if (tid==0) atomicAdd(&flags[10+img],1);
    return;
  }

  if (bx < 12){
    // ------------- per-image top-1000 (1024 threads) -------------
    double* sv=(double*)ush;                          // 4096 dbl  (32KB)
    int*    si=(int*)(ush+32768);                     // 4096 int  (16KB)
    unsigned long long* kbl=(unsigned long long*)(ush+49152);  // 124 (992B)
    int*    hist=(int*)(ush+50144);                   // 256 int
    __shared__ int sI0, sI1, cnt;
    const int img=bx-10;
    if (tid==0){
      while (atomicAdd(&flags[10+img],0) < 5) __builtin_amdgcn_s_sleep(8);
    }
    __syncthreads();
    __threadfence();
    if (tid<124) kbl[tid]=atomicAdd(&keepbuf[(size_t)img*124+tid],0ull);
    __syncthreads();
    const double* sarr=allS+(size_t)img*TOTK;

    unsigned long long chosen=0; int kneed=1000;
    for (int ps=7; ps>=6; --ps){
      int shift=ps*8;
      if (tid<256) hist[tid]=0;
      __syncthreads();
      for (int r=tid;r<TOTK;r+=1024){
        bool kept = (kbl[r>>6]>>(r&63))&1ull;
        double val = kept ? sarr[r] : -HUGE_VAL;
        unsigned long long ik=~mono64(val);
        bool okp=(ps==7)||((ik>>(shift+8))==(chosen>>(shift+8)));
        if (okp) atomicAdd(&hist[(int)((ik>>shift)&255)],1);
      }
      __syncthreads();
      hist_select(hist, kneed, tid, &sI0, &sI1);
      chosen = chosen | ((unsigned long long)sI0<<shift);
      kneed  = sI1;
      __syncthreads();
    }
    const unsigned long long lim = chosen | 0xFFFFFFFFFFFFull;
    if (tid==0) cnt=0;
    __syncthreads();
    for (int r=tid;r<TOTK;r+=1024){
      bool kept = (kbl[r>>6]>>(r&63))&1ull;
      double val = kept ? sarr[r] : -HUGE_VAL;
      unsigned long long ik=~mono64(val);
      if (ik<=lim){ int p=atomicAdd(&cnt,1); if (p<4096){ sv[p]=val; si[p]=r; } }
    }
    __syncthreads();
    int n=cnt<4096?cnt:4096;
    for (int i=tid;i<4096;i+=1024) if (i>=n){ sv[i]=-HUGE_VAL; si[i]=0x7FFFFFFF; }
    bitonic_desc(sv,si,4096,tid,1024);
    for (int j=tid;j<1000;j+=1024){
      out[8000+img*1000+j]=(float)sv[j];
      int idx=si[j];
      const double* b=allB+((size_t)img*TOTK+idx)*4;
      float* ob=out+((size_t)img*1000+j)*4;
      ob[0]=(float)b[0]; ob[1]=(float)b[1]; ob[2]=(float)b[2]; ob[3]=(float)b[3];
    }
    return;
  }

  if (bx == 12){
    // ------------- loss final reduce -------------
    double* sc=(double*)ush; double* sl=(double*)(ush+512);
    if (tid==0){
      while (atomicAdd(&flags[12],0) < 64) __builtin_amdgcn_s_sleep(8);
    }
    __syncthreads();
    __threadfence();
    if (tid<64){ sc[tid]=part[tid*2]; sl[tid]=part[tid*2+1]; }
    __syncthreads();
    for (int s=32;s>0;s>>=1){
      if (tid<s){ sc[tid]+=sc[tid+s]; sl[tid]+=sl[tid+s]; }
      __syncthreads();
    }
    if (tid==0){ out[10000]=(float)(sc[0]/512.0); out[10001]=(float)(sl[0]/512.0); }
    return;
  }

  if (bx < 511){
    // ------------- NMS mask blocks (32 rows each, symmetric j!=i) -------------
    double* Bsh=(double*)ush;                         // up to 8000 dbl (64KB)
    const int rbc[6]={0,63,126,189,237,249};
    int t = bx-13;
    const int img = t/249; t -= img*249;
    int lvl=0; while (lvl<4 && t>=rbc[lvl+1]) lvl++;
    const int i0=(t-rbc[lvl])*32;
    const int K=kl[lvl]; const int nw=(K+63)>>6;
    const double* B=allB+(size_t)(img*TOTK+loff[lvl])*4;
    for (int q=tid;q<K*4;q+=1024) Bsh[q]=B[q];
    __syncthreads();
    const int wv=tid>>6, lane=tid&63;
    for (int rr=0;rr<32;rr++){
      int i=i0+rr;
      if (i>=K) break;
      const double bi0=Bsh[i*4],bi1=Bsh[i*4+1],bi2=Bsh[i*4+2],bi3=Bsh[i*4+3];
      const double areai=(bi2-bi0)*(bi3-bi1);
      for (int w=wv;w<nw;w+=16){
        int j=w*64+lane;
        bool pred=false;
        if (j<K && j!=i){
          double a0=Bsh[j*4],a1=Bsh[j*4+1],a2=Bsh[j*4+2],a3=Bsh[j*4+3];
          double lt0=fmax(bi0,a0), lt1=fmax(bi1,a1);
          double rb0=fmin(bi2,a2), rb1=fmin(bi3,a3);
          double ww=rb0-lt0; if (ww<0.0) ww=0.0;
          double hh=rb1-lt1; if (hh<0.0) hh=0.0;
          double inter=ww*hh;
          double uni=areai+(a2-a0)*(a3-a1)-inter;
          double iou=inter>0.0?inter/uni:0.0;
          pred = iou>0.7;
        }
        unsigned long long m=__ballot(pred);
        if (lane==0) msk[((size_t)img*TOTK+loff[lvl]+i)*32+w]=m;
      }
    }
    __syncthreads();
    if (tid==0){ __threadfence(); atomicAdd(&flags[img*5+lvl],1); }
    return;
  }

  {
    // ------------- loss partial blocks -------------
    double* sc=(double*)ush; double* sl=(double*)(ush+8192);
    const int lb=bx-511;                               // [0,64)
    double cls=0.0, loc=0.0;
    for (int idx=lb*1024+tid; idx<2*R_TOT; idx+=64*1024){
      int l=labels[idx];
      if (l<0) continue;
      double x=logits[idx];
      double fgv=(l==1)?1.0:0.0;
      cls += fmax(x,0.0)-x*fgv+log1p(exp(-fabs(x)));
      if (l==1){
        int img=idx/R_TOT, r=idx-img*R_TOT;
        double a[4]; anchor_of(r,a);
        int m=matched[idx];
        const float* g=gt+img*128+m*4;
        double sw=a[2]-a[0], sh=a[3]-a[1];
        double scx=a[0]+0.5*sw, scy=a[1]+0.5*sh;
        double tw=(double)g[2]-(double)g[0], th=(double)g[3]-(double)g[1];
        double tcx=(double)g[0]+0.5*tw, tcy=(double)g[1]+0.5*th;
        double d0=(tcx-scx)/sw, d1=(tcy-scy)/sh;
        double d2=log(tw/sw), d3=log(th/sh);
        const double* dp=dpred+(size_t)idx*4;
        loc += fabs(dp[0]-d0)+fabs(dp[1]-d1)+fabs(dp[2]-d2)+fabs(dp[3]-d3);
      }
    }
    sc[tid]=cls; sl[tid]=loc; __syncthreads();
    for (int s=512;s>0;s>>=1){
      if (tid<s){ sc[tid]+=sc[tid+s]; sl[tid]+=sl[tid+s]; }
      __syncthreads();
    }
    if (tid==0){
      part[lb*2]=sc[0]; part[lb*2+1]=sl[0];
      __threadfence();
      atomicAdd(&flags[12],1);
    }
  }
}

// ============================================================================
// Host launcher
// ============================================================================
extern "C" void kernel_launch(void* const* d_in, const int* in_sizes, int n_in,
                              void* d_out, int out_size, void* d_ws, size_t ws_size,
                              hipStream_t stream)
{
  (void)in_sizes; (void)n_in; (void)out_size;
  const float* feats[5];
  for (int i=0;i<5;i++) feats[i]=(const float*)d_in[i];
  const float* gt =(const float*)d_in[5];
  const float* cw =(const float*)d_in[6];
  const float* cb =(const float*)d_in[7];
  const float* ow =(const float*)d_in[8];
  const float* ob =(const float*)d_in[9];
  const float* dwt=(const float*)d_in[10];
  const float* dbt=(const float*)d_in[11];
  float* out=(float*)d_out;

  char* p=(char*)d_ws;
  auto carve=[&](size_t nbytes)->char*{ char* q=p; p += (nbytes+255)&~(size_t)255; return q; };
  double* logits =(double*)carve(2ull*R_TOT*8);
  double* dpred  =(double*)carve(2ull*R_TOT*4*8);
  float* cwTf    =(float*)carve(147456ull*4);
  uint32_t* ub   =(uint32_t*)carve(4ull*R_TOT*4);
  int* prelab    =(int*)carve(2ull*R_TOT*4);
  int* matched   =(int*)carve(2ull*R_TOT*4);
  int* labels    =(int*)carve(2ull*R_TOT*4);
  unsigned long long* highest=(unsigned long long*)carve(2*32*8);   // +0:   512B
  int* counts    =(int*)carve(256);                                  // +512: 256B
  int* flags     =(int*)carve(256);                                  // +768: 256B
  double* allS   =(double*)carve(2ull*TOTK*8);
  double* allB   =(double*)carve(2ull*TOTK*4*8);
  unsigned long long* msk=(unsigned long long*)carve(2ull*TOTK*32*8);
  double* part   =(double*)carve(256*2*8);
  unsigned long long* keepbuf=(unsigned long long*)carve(2*124*8);   // init in k_mid2
  if ((size_t)(p-(char*)d_ws) > ws_size) return;

  hipMemsetAsync(highest, 0, 1024, stream);  // highest + counts + flags (contiguous)

  uint32_t a0,b0,a1,b1;
  threefry(0u,42u,0u,2u,&a0,&b0);
  threefry(0u,42u,1u,3u,&a1,&b1);
  uint32_t kf00,kf01,kb00,kb01,kf10,kf11,kb10,kb11;
  { uint32_t c0,d0,c1,d1;
    threefry(a0,a1,0u,2u,&c0,&d0); threefry(a0,a1,1u,3u,&c1,&d1);
    kf00=c0; kf01=c1; kb00=d0; kb01=d1;
    threefry(b0,b1,0u,2u,&c0,&d0); threefry(b0,b1,1u,3u,&c1,&d1);
    kf10=c0; kf11=c1; kb10=d0; kb11=d1; }

  k_pre<<<704, 256, 0, stream>>>(cw, cwTf, gt, highest);
  k_conv_label<<<4775, 256, 0, stream>>>(feats[0],feats[1],feats[2],feats[3],feats[4],
      cwTf,cb,ow,ob,dwt,dbt, logits, dpred,
      gt, highest, prelab, matched, labels, counts,
      ub, kf00,kf01,kb00,kb01,kf10,kf11,kb10,kb11);
  k_mid2<<<14, 1024, 0, stream>>>(ub, prelab, counts, labels, logits, dpred, allS, allB, keepbuf);
  k_mid3post<<<575, 1024, 0, stream>>>(allB, msk, logits, dpred, gt, labels, matched,
      part, allS, flags, keepbuf, out);
}

// Round 17
// 1248.751 us; speedup vs baseline: 1.6732x; 1.0026x over previous
//
#include <hip/hip_runtime.h>
#include <stdint.h>
#include <math.h>

// ============================================================================
// RPN forward (detectron2-style) on MI355X — fp64 ordering-exact pipeline.
// R17: conv launch_bounds (256,3)->(256,4) (VGPR 76 <= 128 cap -> no spill,
// occupancy 32->43%); loss partials moved from mid3post into k_mid2 (blocks
// [14,78) spin on sampling flag; unconditionally deadlock-free: 78 blocks all
// co-resident) so mid2's 14-block dispatch stops running at throttled clocks.
// ============================================================================

#define R_TOT   130944
#define HALF_R  65472
#define TOTK    7920
#define SCALE_CLAMP 4.135166556742356  // log(1000/16)

// ---------------- threefry2x32-20 (JAX-compatible) ----------------
__host__ __device__ inline void threefry(uint32_t k0, uint32_t k1,
                                         uint32_t x0, uint32_t x1,
                                         uint32_t* o0, uint32_t* o1)
{
  uint32_t ks[3]; ks[0]=k0; ks[1]=k1; ks[2]=k0^k1^0x1BD11BDAu;
  x0 += ks[0]; x1 += ks[1];
  const uint32_t rot0[4] = {13u,15u,26u,6u};
  const uint32_t rot1[4] = {17u,29u,16u,24u};
  for (int i = 0; i < 5; i++){
    const uint32_t* rot = (i & 1) ? rot1 : rot0;
    for (int q = 0; q < 4; q++){
      x0 += x1;
      x1 = (x1 << rot[q]) | (x1 >> (32u - rot[q]));
      x1 ^= x0;
    }
    x0 += ks[(i+1)%3];
    x1 += ks[(i+2)%3] + (uint32_t)(i+1);
  }
  *o0 = x0; *o1 = x1;
}

// ---------------- helpers ----------------
__device__ inline unsigned long long mono64(double v){
  unsigned long long b = (unsigned long long)__double_as_longlong(v);
  return (b & 0x8000000000000000ull) ? ~b : (b | 0x8000000000000000ull);
}

__device__ __forceinline__ double iou_cf(double g0,double g1,double g2,double g3,
                                         double a0,double a1,double a2,double a3){
  #pragma clang fp contract(off)
  double lt0 = fmax(g0,a0), lt1 = fmax(g1,a1);
  double rb0 = fmin(g2,a2), rb1 = fmin(g3,a3);
  double w = rb0-lt0; if (w<0.0) w=0.0;
  double h = rb1-lt1; if (h<0.0) h=0.0;
  double inter = w*h;
  double aa = (g2-g0)*(g3-g1);
  double ab = (a2-a0)*(a3-a1);
  double uni = aa+ab-inter;
  return inter>0.0 ? inter/uni : 0.0;
}

__device__ __forceinline__ void anchor_of(int r, double* o){
  #pragma clang fp contract(off)
  const int    base[5]={0,98304,122880,129024,130560};
  const int    Wl[5]  ={256,128,64,32,16};
  const double strd[5]={4.0,8.0,16.0,32.0,64.0};
  const double size[5]={32.0,64.0,128.0,256.0,512.0};
  const double ratio[3]={0.5,1.0,2.0};
  int l=0; while (l<4 && r>=base[l+1]) l++;
  int rr=r-base[l]; int pix=rr/3; int a=rr-pix*3;
  int x=pix%Wl[l], y=pix/Wl[l];
  double w=sqrt(size[l]*size[l]/ratio[a]);
  double h=w*ratio[a];
  double sx=(double)x*strd[l], sy=(double)y*strd[l];
  o[0]=sx-0.5*w; o[1]=sy-0.5*h; o[2]=sx+0.5*w; o[3]=sy+0.5*h;
}

// apply_deltas + clip
__device__ __forceinline__ void decode_box(int ridx, const double* __restrict__ d,
                                           double* __restrict__ o){
  double a[4]; anchor_of(ridx,a);
  double w=a[2]-a[0], h=a[3]-a[1];
  double cx=a[0]+0.5*w, cy=a[1]+0.5*h;
  double dw=fmin(d[2],SCALE_CLAMP), dh=fmin(d[3],SCALE_CLAMP);
  double pcx=d[0]*w+cx, pcy=d[1]*h+cy;
  double pw=exp(dw)*w, ph=exp(dh)*h;
  double x1=pcx-0.5*pw, y1=pcy-0.5*ph;
  double x2=pcx+0.5*pw, y2=pcy+0.5*ph;
  o[0]=fmin(fmax(x1,0.0),1024.0); o[1]=fmin(fmax(y1,0.0),512.0);
  o[2]=fmin(fmax(x2,0.0),1024.0); o[3]=fmin(fmax(y2,0.0),512.0);
}

__device__ inline void bitonic_desc(double* sv, int* si, int M, int tid, int nthr){
  for (int k=2;k<=M;k<<=1)
    for (int j=k>>1;j>0;j>>=1){
      __syncthreads();
      for (int i=tid;i<M;i+=nthr){
        int ixj=i^j;
        if (ixj>i){
          double va=sv[i], vb=sv[ixj]; int ia=si[i], ib=si[ixj];
          bool before = (va>vb) || (va==vb && ia<ib);
          bool up = ((i&k)==0);
          if (up ? !before : before){ sv[i]=vb; sv[ixj]=va; si[i]=ib; si[ixj]=ia; }
        }
      }
    }
  __syncthreads();
}

__device__ inline void bitonic_asc_u(uint32_t* sk, int* si, int M, int tid, int nthr){
  for (int k=2;k<=M;k<<=1)
    for (int j=k>>1;j>0;j>>=1){
      __syncthreads();
      for (int i=tid;i<M;i+=nthr){
        int ixj=i^j;
        if (ixj>i){
          uint32_t ka=sk[i], kb=sk[ixj]; int ia=si[i], ib=si[ixj];
          bool before = (ka<kb) || (ka==kb && ia<ib);
          bool up = ((i&k)==0);
          if (up ? !before : before){ sk[i]=kb; sk[ixj]=ka; si[i]=ib; si[ixj]=ia; }
        }
      }
    }
  __syncthreads();
}

// Parallel select over hist[256] (in-place inclusive scan). blockDim >= 256.
__device__ inline void hist_select(int* hist, int kneed, int tid,
                                   int* shb, int* shk){
  for (int off=1; off<256; off<<=1){
    int v=0;
    if (tid<256 && tid>=off) v=hist[tid-off];
    __syncthreads();
    if (tid<256) hist[tid]+=v;
    __syncthreads();
  }
  if (tid<256){
    int prev = tid ? hist[tid-1] : 0;
    if (prev < kneed && kneed <= hist[tid]){ *shb=tid; *shk=kneed-prev; }
    if (tid==255 && kneed > hist[255]){ *shb=255; *shk=kneed-hist[254]; }
  }
  __syncthreads();
}

// ============================================================================
// Kernel A (k_pre): [0,576): weight permute cw->cwTf[ci][k9][cc] f32.
//                   [576,704): per-gt max IoU (gtmax).
// ============================================================================
__global__ __launch_bounds__(256) void k_pre(const float* __restrict__ cw,
    float* __restrict__ cwTf, const float* __restrict__ gt,
    unsigned long long* __restrict__ highest)
{
  const int bx=blockIdx.x, tid=threadIdx.x;
  if (bx < 576){
    int o = bx*256 + tid;
    if (o >= 147456) return;
    int cc = o & 127; int t = o >> 7;
    int k9 = t % 9;  int ci = t / 9;
    cwTf[(size_t)(ci*9+k9)*128 + cc] = cw[(size_t)cc*1152 + ci*9 + k9];
  } else {
    __shared__ double gts[128];
    __shared__ unsigned long long lmax[32];
    const int gb=bx-576;
    const int img=gb>>6, b=gb&63;
    if (tid<128) gts[tid]=(double)gt[img*128+tid];
    if (tid<32) lmax[tid]=0ull;
    __syncthreads();
    double gm[32];
    #pragma unroll
    for (int g=0;g<32;g++) gm[g]=0.0;
    for (int r=b*256+tid; r<R_TOT; r+=64*256){
      double a[4]; anchor_of(r,a);
      #pragma unroll
      for (int g=0;g<32;g++){
        double v=iou_cf(gts[g*4],gts[g*4+1],gts[g*4+2],gts[g*4+3],a[0],a[1],a[2],a[3]);
        gm[g]=fmax(gm[g],v);
      }
    }
    #pragma unroll
    for (int g=0;g<32;g++){
      double v=gm[g];
      #pragma unroll
      for (int off=1; off<64; off<<=1) v=fmax(v,__shfl_xor(v,off));
      if ((tid&63)==0) atomicMax(&lmax[g],(unsigned long long)__double_as_longlong(v));
    }
    __syncthreads();
    if (tid<32) atomicMax(&highest[img*32+tid], lmax[tid]);
  }
}

// ============================================================================
// Kernel B (k_conv_label): [0,2728): conv+heads. [2728,3752): labels.
// [3752,4775): threefry ubits. launch_bounds(256,4): VGPR cap 128 >= 76 used.
// ============================================================================
#define CTH 4
#define CTW 8

__global__ __launch_bounds__(256,4) void k_conv_label(
    const float* __restrict__ f2, const float* __restrict__ f3,
    const float* __restrict__ f4, const float* __restrict__ f5,
    const float* __restrict__ f6,
    const float* __restrict__ cwTf, const float* __restrict__ cb,
    const float* __restrict__ ow, const float* __restrict__ ob,
    const float* __restrict__ dwt, const float* __restrict__ dbt,
    double* __restrict__ logits, double* __restrict__ dpred,
    const float* __restrict__ gt, const unsigned long long* __restrict__ highest,
    int* __restrict__ prelab, int* __restrict__ matched,
    int* __restrict__ labels, int* __restrict__ counts,
    uint32_t* __restrict__ ub,
    uint32_t kf00,uint32_t kf01,uint32_t kb00,uint32_t kb01,
    uint32_t kf10,uint32_t kf11,uint32_t kb10,uint32_t kb11)
{
  __shared__ double fshd[4][6][12];
  __shared__ __align__(16) char ush[18432];   // wshF [4][9][128] f32 / hshp [128][17] dbl / label arrays
  float*  wshF = (float*)ush;
  double* hshp = (double*)ush;
  __shared__ float hw[15*128];
  __shared__ float hb[15];

  const int tid=threadIdx.x;
  const int vbid = blockIdx.x;

  if (vbid >= 3752){
    // ------------------- ubits path -------------------
    int j = (vbid-3752)*256 + tid;
    if (j >= 2*R_TOT) return;
    int slot = j / HALF_R; int t = j - slot*HALF_R;
    uint32_t k0,k1;
    if      (slot==0){k0=kf00;k1=kf01;}
    else if (slot==1){k0=kb00;k1=kb01;}
    else if (slot==2){k0=kf10;k1=kf11;}
    else             {k0=kb10;k1=kb11;}
    uint32_t o0,o1;
    threefry(k0,k1,(uint32_t)t,(uint32_t)(t+HALF_R),&o0,&o1);
    ub[(size_t)slot*R_TOT+t]=o0;
    ub[(size_t)slot*R_TOT+t+HALF_R]=o1;
    return;
  }

  if (vbid >= 2728){
    // ------------------- label path -------------------
    double* gts=(double*)ush;                        // [128]
    double* hg =(double*)(ush+1024);                 // [32]
    int* wfg=(int*)(ush+1280); int* wbg=(int*)(ush+1296);
    const int lb=vbid-2728;
    const int img=lb>>9, blk=lb&511;
    if (tid<128) gts[tid]=(double)gt[img*128+tid];
    if (tid<32)  hg[tid]=__longlong_as_double((long long)highest[img*32+tid]);
    __syncthreads();
    int r=blk*256+tid;
    const bool ok=(r<R_TOT);
    int lab=-1, bi=0;
    if (ok){
      double a[4]; anchor_of(r,a);
      double best=-1.0; bool lq=false;
      #pragma unroll
      for (int g=0;g<32;g++){
        double v=iou_cf(gts[g*4],gts[g*4+1],gts[g*4+2],gts[g*4+3],a[0],a[1],a[2],a[3]);
        if (v>best){ best=v; bi=g; }
        if (hg[g]>0.0 && v==hg[g]) lq=true;
      }
      lab = lq ? 1 : (best>=0.7 ? 1 : (best>=0.3 ? -1 : 0));
      prelab [(size_t)img*R_TOT+r]=lab;
      matched[(size_t)img*R_TOT+r]=bi;
      labels [(size_t)img*R_TOT+r]=-1;
    }
    unsigned long long bf=__ballot(ok && lab==1);
    unsigned long long bb=__ballot(ok && lab==0);
    const int wid=tid>>6, lane=tid&63;
    if (lane==0){ wfg[wid]=__popcll(bf); wbg[wid]=__popcll(bb); }
    __syncthreads();
    if (tid==0){
      int fcnt=wfg[0]+wfg[1]+wfg[2]+wfg[3];
      int bcnt=wbg[0]+wbg[1]+wbg[2]+wbg[3];
      if (fcnt) atomicAdd(&counts[img*2+0],fcnt);
      if (bcnt) atomicAdd(&counts[img*2+1],bcnt);
    }
    return;
  }

  // ------------------- conv path -------------------
  const int cumt[6]={0,2048,2560,2688,2720,2728};
  const int Hs[5]={128,64,32,16,8}, Wl[5]={256,128,64,32,16};
  const int rbs[5]={0,98304,122880,129024,130560};
  const int lgx[5]={5,4,3,2,1};

  int bid=vbid;
  int lvl=0;
  while (lvl<4 && bid>=cumt[lvl+1]) lvl++;
  int t=bid-cumt[lvl];
  const int img=t&1; const int tt=t>>1;
  const int H=Hs[lvl], W=Wl[lvl], rbase=rbs[lvl];
  const int tx=tt&((1<<lgx[lvl])-1), ty=tt>>lgx[lvl];
  const int x0=tx*CTW, y0=ty*CTH;
  const float* f = lvl==0?f2: lvl==1?f3: lvl==2?f4: lvl==3?f5: f6;

  for (int i=tid;i<15*128;i+=256){
    int o=i>>7, c=i&127;
    hw[i]=(o<3)?ow[o*128+c]:dwt[(o-3)*128+c];
  }
  if (tid<15) hb[tid]=(tid<3)?ob[tid]:dbt[tid-3];

  const int c=tid&127, half=tid>>7;
  double acc[16];
  #pragma unroll
  for (int i=0;i<16;i++) acc[i]=0.0;

  const float* fimg = f + (size_t)img*128*H*W;

  const bool fin_act = (tid < 240);
  int ci_f=0,dy_f=0,dx_f=0; bool fin_valid=false;
  const float* fptr=fimg;
  if (fin_act){
    ci_f=tid/60; int rem=tid-ci_f*60; dy_f=rem/10; dx_f=rem-dy_f*10;
    int y=y0-1+dy_f, x=x0-1+dx_f;
    fin_valid = (y>=0&&y<H&&x>=0&&x<W);
    fptr = fimg + (size_t)ci_f*H*W + (fin_valid ? ((size_t)y*W+x) : 0);
  }
  const size_t fstep=(size_t)4*H*W;
  const float2* wsrc=(const float2*)cwTf;

  float fin_pf=0.f; float2 wpf[9];
  if (fin_act){ fin_pf = fin_valid ? *fptr : 0.f; fptr += fstep; }
  #pragma unroll
  for (int j2=0;j2<9;j2++) wpf[j2]=wsrc[tid+j2*256];

  for (int ci0=0; ci0<128; ci0+=4){
    __syncthreads();                         // prior compute done reading LDS
    if (fin_act) fshd[ci_f][dy_f][dx_f]=(double)fin_pf;
    { float2* wdst=(float2*)wshF;
      #pragma unroll
      for (int j2=0;j2<9;j2++) wdst[tid+j2*256]=wpf[j2]; }
    if (ci0+4<128){                          // issue next chunk (hidden by compute)
      if (fin_act){ fin_pf = fin_valid ? *fptr : 0.f; fptr += fstep; }
      const float2* wn = wsrc + (size_t)(ci0+4)*576;
      #pragma unroll
      for (int j2=0;j2<9;j2++) wpf[j2]=wn[tid+j2*256];
    }
    __syncthreads();                         // LDS ready
    #pragma unroll
    for (int ci=0;ci<4;ci++){
      double w9d[9];
      #pragma unroll
      for (int k=0;k<9;k++) w9d[k]=(double)wshF[(ci*9+k)*128 + c];
      #pragma unroll
      for (int irl=0;irl<4;irl++){
        int ir=half*2+irl;
        double rowb[10];
        #pragma unroll
        for (int q=0;q<10;q++) rowb[q]=fshd[ci][ir][q];
        #pragma unroll
        for (int orl=0;orl<2;orl++){
          int ky=irl-orl;
          if (ky<0||ky>2) continue;
          #pragma unroll
          for (int px=0;px<8;px++){
            double s=acc[orl*8+px];
            #pragma unroll
            for (int kx=0;kx<3;kx++) s += w9d[ky*3+kx]*rowb[px+kx];
            acc[orl*8+px]=s;
          }
        }
      }
    }
  }
  // ---- epilogue: two pixel halves (hshp [128][17], aliases wshF) ----
  double bc=(double)cb[c];
  __syncthreads();                           // wshF reads done
  if (half==0){
    #pragma unroll
    for (int pp=0;pp<16;pp++){
      double hv=acc[pp]+bc; if (hv<0.0) hv=0.0;
      hshp[c*17+pp]=hv;
    }
  }
  __syncthreads();
  for (int hp=0;hp<2;hp++){
    if (tid<240){
      int o=tid>>4, p=tid&15;
      double s=(double)hb[o];
      for (int c2=0;c2<128;c2++) s += (double)hw[o*128+c2]*hshp[c2*17+p];
      int pg=hp*16+p;
      int py=pg>>3, px=pg&7;
      int gy=y0+py, gx=x0+px;
      long long pix=(long long)gy*W+gx;
      size_t rb=(size_t)rbase+(size_t)pix*3;
      if (o<3) logits[(size_t)img*R_TOT+rb+o]=s;
      else { int a=(o-3)>>2, jj=(o-3)&3; dpred[((size_t)img*R_TOT+rb+a)*4+jj]=s; }
    }
    if (hp==0){
      __syncthreads();                       // heads done reading half 0
      if (half==1){
        #pragma unroll
        for (int pp=0;pp<16;pp++){
          double hv=acc[pp]+bc; if (hv<0.0) hv=0.0;
          hshp[c*17+pp]=hv;
        }
      }
      __syncthreads();                       // half 1 ready
    }
  }
}

// ============================================================================
// Kernel C (k_mid2, 78 blocks x 1024 thr):
//  [0,4):  fg/bg sampling -> flags[13]++ when done.
//  [4,14): top-k with on-the-fly box decode; lvl0 blocks init keepbuf.
//  [14,78): loss partials (spin flags[13]==4) -> part[], flags[12]++.
// All 78 blocks co-resident (3/CU) -> spin is unconditionally deadlock-free.
// ============================================================================
__global__ __launch_bounds__(1024) void k_mid2(const uint32_t* __restrict__ ub,
    const int* __restrict__ prelab, const int* __restrict__ counts,
    int* __restrict__ labels,
    const double* __restrict__ logits, const double* __restrict__ dpred,
    double* __restrict__ allS, double* __restrict__ allB,
    unsigned long long* __restrict__ keepbuf,
    const float* __restrict__ gt, const int* __restrict__ matched,
    double* __restrict__ part, int* __restrict__ flags)
{
  __shared__ __align__(16) char buf[49152];
  __shared__ int hist[256];
  __shared__ int sI0, sI1;
  __shared__ int cnt;
  const int tid=threadIdx.x;

  if (blockIdx.x < 4){
    // ------------------- sampling -------------------
    uint32_t* skey=(uint32_t*)buf; int* sidx=(int*)(buf+16384);
    const int img=blockIdx.x>>1, cls=blockIdx.x&1;
    const int cfg=counts[img*2+0], cbg=counts[img*2+1];
    const int num_fg=cfg<128?cfg:128;
    const int cap_bg=256-num_fg;
    const int num=cls?(cbg<cap_bg?cbg:cap_bg):num_fg;
    if (num<=0){
      if (tid==0){ __threadfence(); atomicAdd(&flags[13],1); }
      return;
    }
    const int want=cls?0:1;
    const int sel=want;
    const uint32_t* u=ub+(size_t)(img*2+cls)*R_TOT;
    const int* pl=prelab+(size_t)img*R_TOT;
    int* lab=labels+(size_t)img*R_TOT;

    for (int b=tid;b<256;b+=1024) hist[b]=0;
    if (tid==0) cnt=0;
    __syncthreads();
    #pragma unroll 4
    for (int r=tid;r<R_TOT;r+=1024){
      int plr = pl[r];
      uint32_t key = u[r]>>9;
      if (plr==want) atomicAdd(&hist[key>>15],1);
    }
    __syncthreads();
    hist_select(hist, num, tid, &sI0, &sI1);
    const uint32_t bsel=(uint32_t)sI0; const int kneed=sI1;
    #pragma unroll 4
    for (int r=tid;r<R_TOT;r+=1024){
      int plr = pl[r];
      uint32_t key = u[r]>>9;
      if (plr==want){
        uint32_t t8=key>>15;
        if (t8<bsel) lab[r]=sel;
        else if (t8==bsel){ int p=atomicAdd(&cnt,1); if (p<4096){ skey[p]=key; sidx[p]=r; } }
      }
    }
    __syncthreads();
    int n=cnt<4096?cnt:4096;
    for (int i=tid;i<4096;i+=1024) if (i>=n){ skey[i]=0xFFFFFFFFu; sidx[i]=0x7FFFFFFF; }
    bitonic_asc_u(skey,sidx,4096,tid,1024);
    int take = kneed<n?kneed:n;
    for (int i=tid;i<take;i+=1024) lab[sidx[i]]=sel;
    __syncthreads();
    if (tid==0){ __threadfence(); atomicAdd(&flags[13],1); }
  } else if (blockIdx.x < 14){
    // ------------------- top-k -------------------
    double* sv=(double*)buf; int* si=(int*)(buf+32768);
    const int Rl[5]   ={98304,24576,6144,1536,384};
    const int kl[5]   ={2000,2000,2000,1536,384};
    const int lbase[5]={0,98304,122880,129024,130560};
    const int loff[5] ={0,2000,4000,6000,7536};
    const int bb=blockIdx.x-4;
    const int lvl=bb%5, img=bb/5;
    if (lvl==0 && tid<124) keepbuf[img*124+tid]=~0ull;   // init for the scan
    const int Rn=Rl[lvl], K=kl[lvl];
    const double* lg=logits+(size_t)img*R_TOT+lbase[lvl];

    unsigned long long chosen=0; int kneed=K;
    for (int ps=7; ps>=6; --ps){
      int shift=ps*8;
      for (int b=tid;b<256;b+=1024) hist[b]=0;
      __syncthreads();
      #pragma unroll 4
      for (int r=tid;r<Rn;r+=1024){
        unsigned long long ik=~mono64(lg[r]);
        bool okp=(ps==7)||((ik>>(shift+8))==(chosen>>(shift+8)));
        if (okp) atomicAdd(&hist[(int)((ik>>shift)&255)],1);
      }
      __syncthreads();
      hist_select(hist, kneed, tid, &sI0, &sI1);
      chosen = chosen | ((unsigned long long)sI0<<shift);
      kneed  = sI1;
      __syncthreads();
    }
    const unsigned long long lim = chosen | 0xFFFFFFFFFFFFull;
    if (tid==0) cnt=0;
    __syncthreads();
    #pragma unroll 4
    for (int r=tid;r<Rn;r+=1024){
      unsigned long long ik=~mono64(lg[r]);
      if (ik<=lim){ int p=atomicAdd(&cnt,1); if (p<4096){ sv[p]=lg[r]; si[p]=r; } }
    }
    __syncthreads();
    int n=cnt<4096?cnt:4096;
    for (int i=tid;i<4096;i+=1024) if (i>=n){ sv[i]=-HUGE_VAL; si[i]=0x7FFFFFFF; }
    bitonic_desc(sv,si,4096,tid,1024);
    for (int j=tid;j<K;j+=1024){
      double v=sv[j]; int r=si[j];
      size_t slot=(size_t)img*TOTK+loff[lvl]+j;
      allS[slot]=v;
      int ridx=lbase[lvl]+r;
      double bx[4];
      decode_box(ridx, dpred+((size_t)img*R_TOT+ridx)*4, bx);
      allB[slot*4+0]=bx[0]; allB[slot*4+1]=bx[1]; allB[slot*4+2]=bx[2]; allB[slot*4+3]=bx[3];
    }
  } else {
    // ------------------- loss partials (spin on sampling) -------------------
    double* sc=(double*)buf; double* sl=(double*)(buf+8192);
    const int lb=blockIdx.x-14;                        // [0,64)
    if (tid==0){
      while (atomicAdd(&flags[13],0) < 4) __builtin_amdgcn_s_sleep(8);
    }
    __syncthreads();
    __threadfence();
    double cls=0.0, loc=0.0;
    for (int idx=lb*1024+tid; idx<2*R_TOT; idx+=64*1024){
      int l=labels[idx];
      if (l<0) continue;
      double x=logits[idx];
      double fgv=(l==1)?1.0:0.0;
      cls += fmax(x,0.0)-x*fgv+log1p(exp(-fabs(x)));
      if (l==1){
        int img=idx/R_TOT, r=idx-img*R_TOT;
        double a[4]; anchor_of(r,a);
        int m=matched[idx];
        const float* g=gt+img*128+m*4;
        double sw=a[2]-a[0], sh=a[3]-a[1];
        double scx=a[0]+0.5*sw, scy=a[1]+0.5*sh;
        double tw=(double)g[2]-(double)g[0], th=(double)g[3]-(double)g[1];
        double tcx=(double)g[0]+0.5*tw, tcy=(double)g[1]+0.5*th;
        double d0=(tcx-scx)/sw, d1=(tcy-scy)/sh;
        double d2=log(tw/sw), d3=log(th/sh);
        const double* dp=dpred+(size_t)idx*4;
        loc += fabs(dp[0]-d0)+fabs(dp[1]-d1)+fabs(dp[2]-d2)+fabs(dp[3]-d3);
      }
    }
    sc[tid]=cls; sl[tid]=loc; __syncthreads();
    for (int s=512;s>0;s>>=1){
      if (tid<s){ sc[tid]+=sc[tid+s]; sl[tid]+=sl[tid+s]; }
      __syncthreads();
    }
    if (tid==0){
      part[lb*2]=sc[0]; part[lb*2+1]=sl[0];
      __threadfence();
      atomicAdd(&flags[12],1);
    }
  }
}

// ============================================================================
// Kernel D (k_mid3post, 511 blocks x 1024 thr):
//  [0,10):  ballot fixed-point NMS scan; spin flags[img*5+lvl]==MBLK[lvl].
//  [10,12): per-image top-1000; spin flags[10+img]==5.
//  [12]:    loss final reduce (flags[12]==64 already set by k_mid2).
//  [13,511): NMS mask, 32 rows/block, SYMMETRIC (j!=i), boxes in LDS.
// ============================================================================
__global__ __launch_bounds__(1024) void k_mid3post(const double* __restrict__ allB,
    unsigned long long* __restrict__ msk,
    double* __restrict__ part,
    const double* __restrict__ allS, int* __restrict__ flags,
    unsigned long long* __restrict__ keepbuf, float* __restrict__ out)
{
  __shared__ __align__(16) char ush[64000];
  const int tid=threadIdx.x, bx=blockIdx.x;
  const int kl[5]  ={2000,2000,2000,1536,384};
  const int loff[5]={0,2000,4000,6000,7536};
  const int MBLK[5]={63,63,63,48,12};

  if (bx < 10){
    // ------------- ballot fixed-point greedy NMS scan (wave 0 only) -------------
    if (tid >= 64) return;
    const int lvl=bx%5, img=bx/5;
    const int K=kl[lvl], off=loff[lvl], nw=(K+63)>>6;
    const int lane=tid;
    {
      const int target=MBLK[lvl];
      while (true){
        int v = (lane==0) ? atomicAdd(&flags[img*5+lvl],0) : 0;
        v = __shfl(v,0);
        if (v>=target) break;
        __builtin_amdgcn_s_sleep(8);
      }
      __threadfence();
    }
    const double* B=allB+(size_t)(img*TOTK+off)*4;
    const unsigned long long* M=msk+((size_t)img*TOTK+off)*32;
    unsigned long long keepw=0ull;
    if (lane<nw){
      for (int b=0;b<64;b++){
        int j=lane*64+b;
        if (j<K){
          double x1=B[(size_t)j*4],y1=B[(size_t)j*4+1],x2=B[(size_t)j*4+2],y2=B[(size_t)j*4+3];
          if ((x2-x1)>0.0 && (y2-y1)>0.0) keepw|=(1ull<<b);
        }
      }
    }
    for (int w=0; w<nw; w++){
      unsigned long long vw = __shfl(keepw, w);
      int row = w*64 + lane;
      unsigned long long mrow = (row<K) ? M[(size_t)row*32+w] : 0ull;
      unsigned long long m_lo = lane ? (mrow & ((1ull<<lane)-1ull)) : 0ull;
      const bool validL = (vw>>lane)&1ull;
      unsigned long long kmask = vw;
      while (true){
        bool s = validL && ((m_lo & kmask)==0ull);
        unsigned long long nk = __ballot(s);
        if (nk==kmask) break;
        kmask = nk;
      }
      if (lane==w) keepw = kmask;
      if (lane>w && lane<nw){
        unsigned long long sup=0ull;
        for (int b=0;b<64;b++){
          if ((kmask>>b)&1ull) sup |= M[(size_t)(w*64+b)*32+lane];
        }
        keepw &= ~sup;
      }
    }
    if (lane<nw){
      int nvalid = K - lane*64; if (nvalid>64) nvalid=64;
      unsigned long long vm = (nvalid>=64) ? ~0ull : ((1ull<<nvalid)-1ull);
      unsigned long long cbits = (~keepw) & vm;
      int gbase = off + lane*64;
      int w0 = gbase>>6, sh = gbase&63;
      unsigned long long* kb = keepbuf + (size_t)img*124;
      if (sh==0){
        if (cbits) atomicAnd(&kb[w0], ~cbits);
      } else {
        unsigned long long lo = cbits << sh;
        unsigned long long hi = cbits >> (64-sh);
        if (lo) atomicAnd(&kb[w0],   ~lo);
        if (hi) atomicAnd(&kb[w0+1], ~hi);
      }
    }
    __threadfence();
    if (tid==0) atomicAdd(&flags[10+img],1);
    return;
  }

  if (bx < 12){
    // ------------- per-image top-1000 (1024 threads) -------------
    double* sv=(double*)ush;                          // 4096 dbl  (32KB)
    int*    si=(int*)(ush+32768);                     // 4096 int  (16KB)
    unsigned long long* kbl=(unsigned long long*)(ush+49152);  // 124 (992B)
    int*    hist=(int*)(ush+50144);                   // 256 int
    __shared__ int sI0, sI1, cnt;
    const int img=bx-10;
    if (tid==0){
      while (atomicAdd(&flags[10+img],0) < 5) __builtin_amdgcn_s_sleep(8);
    }
    __syncthreads();
    __threadfence();
    if (tid<124) kbl[tid]=atomicAdd(&keepbuf[(size_t)img*124+tid],0ull);
    __syncthreads();
    const double* sarr=allS+(size_t)img*TOTK;

    unsigned long long chosen=0; int kneed=1000;
    for (int ps=7; ps>=6; --ps){
      int shift=ps*8;
      if (tid<256) hist[tid]=0;
      __syncthreads();
      for (int r=tid;r<TOTK;r+=1024){
        bool kept = (kbl[r>>6]>>(r&63))&1ull;
        double val = kept ? sarr[r] : -HUGE_VAL;
        unsigned long long ik=~mono64(val);
        bool okp=(ps==7)||((ik>>(shift+8))==(chosen>>(shift+8)));
        if (okp) atomicAdd(&hist[(int)((ik>>shift)&255)],1);
      }
      __syncthreads();
      hist_select(hist, kneed, tid, &sI0, &sI1);
      chosen = chosen | ((unsigned long long)sI0<<shift);
      kneed  = sI1;
      __syncthreads();
    }
    const unsigned long long lim = chosen | 0xFFFFFFFFFFFFull;
    if (tid==0) cnt=0;
    __syncthreads();
    for (int r=tid;r<TOTK;r+=1024){
      bool kept = (kbl[r>>6]>>(r&63))&1ull;
      double val = kept ? sarr[r] : -HUGE_VAL;
      unsigned long long ik=~mono64(val);
      if (ik<=lim){ int p=atomicAdd(&cnt,1); if (p<4096){ sv[p]=val; si[p]=r; } }
    }
    __syncthreads();
    int n=cnt<4096?cnt:4096;
    for (int i=tid;i<4096;i+=1024) if (i>=n){ sv[i]=-HUGE_VAL; si[i]=0x7FFFFFFF; }
    bitonic_desc(sv,si,4096,tid,1024);
    for (int j=tid;j<1000;j+=1024){
      out[8000+img*1000+j]=(float)sv[j];
      int idx=si[j];
      const double* b=allB+((size_t)img*TOTK+idx)*4;
      float* ob=out+((size_t)img*1000+j)*4;
      ob[0]=(float)b[0]; ob[1]=(float)b[1]; ob[2]=(float)b[2]; ob[3]=(float)b[3];
    }
    return;
  }

  if (bx == 12){
    // ------------- loss final reduce (partials from k_mid2, already done) -------------
    double* sc=(double*)ush; double* sl=(double*)(ush+512);
    if (tid==0){
      while (atomicAdd(&flags[12],0) < 64) __builtin_amdgcn_s_sleep(8);
    }
    __syncthreads();
    __threadfence();
    if (tid<64){ sc[tid]=part[tid*2]; sl[tid]=part[tid*2+1]; }
    __syncthreads();
    for (int s=32;s>0;s>>=1){
      if (tid<s){ sc[tid]+=sc[tid+s]; sl[tid]+=sl[tid+s]; }
      __syncthreads();
    }
    if (tid==0){ out[10000]=(float)(sc[0]/512.0); out[10001]=(float)(sl[0]/512.0); }
    return;
  }

  {
    // ------------- NMS mask blocks (32 rows each, symmetric j!=i) -------------
    double* Bsh=(double*)ush;                         // up to 8000 dbl (64KB)
    const int rbc[6]={0,63,126,189,237,249};
    int t = bx-13;
    const int img = t/249; t -= img*249;
    int lvl=0; while (lvl<4 && t>=rbc[lvl+1]) lvl++;
    const int i0=(t-rbc[lvl])*32;
    const int K=kl[lvl]; const int nw=(K+63)>>6;
    const double* B=allB+(size_t)(img*TOTK+loff[lvl])*4;
    for (int q=tid;q<K*4;q+=1024) Bsh[q]=B[q];
    __syncthreads();
    const int wv=tid>>6, lane=tid&63;
    for (int rr=0;rr<32;rr++){
      int i=i0+rr;
      if (i>=K) break;
      const double bi0=Bsh[i*4],bi1=Bsh[i*4+1],bi2=Bsh[i*4+2],bi3=Bsh[i*4+3];
      const double areai=(bi2-bi0)*(bi3-bi1);
      for (int w=wv;w<nw;w+=16){
        int j=w*64+lane;
        bool pred=false;
        if (j<K && j!=i){
          double a0=Bsh[j*4],a1=Bsh[j*4+1],a2=Bsh[j*4+2],a3=Bsh[j*4+3];
          double lt0=fmax(bi0,a0), lt1=fmax(bi1,a1);
          double rb0=fmin(bi2,a2), rb1=fmin(bi3,a3);
          double ww=rb0-lt0; if (ww<0.0) ww=0.0;
          double hh=rb1-lt1; if (hh<0.0) hh=0.0;
          double inter=ww*hh;
          double uni=areai+(a2-a0)*(a3-a1)-inter;
          double iou=inter>0.0?inter/uni:0.0;
          pred = iou>0.7;
        }
        unsigned long long m=__ballot(pred);
        if (lane==0) msk[((size_t)img*TOTK+loff[lvl]+i)*32+w]=m;
      }
    }
    __syncthreads();
    if (tid==0){ __threadfence(); atomicAdd(&flags[img*5+lvl],1); }
  }
}

// ============================================================================
// Host launcher
// ============================================================================
extern "C" void kernel_launch(void* const* d_in, const int* in_sizes, int n_in,
                              void* d_out, int out_size, void* d_ws, size_t ws_size,
                              hipStream_t stream)
{
  (void)in_sizes; (void)n_in; (void)out_size;
  const float* feats[5];
  for (int i=0;i<5;i++) feats[i]=(const float*)d_in[i];
  const float* gt =(const float*)d_in[5];
  const float* cw =(const float*)d_in[6];
  const float* cb =(const float*)d_in[7];
  const float* ow =(const float*)d_in[8];
  const float* ob =(const float*)d_in[9];
  const float* dwt=(const float*)d_in[10];
  const float* dbt=(const float*)d_in[11];
  float* out=(float*)d_out;

  char* p=(char*)d_ws;
  auto carve=[&](size_t nbytes)->char*{ char* q=p; p += (nbytes+255)&~(size_t)255; return q; };
  double* logits =(double*)carve(2ull*R_TOT*8);
  double* dpred  =(double*)carve(2ull*R_TOT*4*8);
  float* cwTf    =(float*)carve(147456ull*4);
  uint32_t* ub   =(uint32_t*)carve(4ull*R_TOT*4);
  int* prelab    =(int*)carve(2ull*R_TOT*4);
  int* matched   =(int*)carve(2ull*R_TOT*4);
  int* labels    =(int*)carve(2ull*R_TOT*4);
  unsigned long long* highest=(unsigned long long*)carve(2*32*8);   // +0:   512B
  int* counts    =(int*)carve(256);                                  // +512: 256B
  int* flags     =(int*)carve(256);                                  // +768: 256B
  double* allS   =(double*)carve(2ull*TOTK*8);
  double* allB   =(double*)carve(2ull*TOTK*4*8);
  unsigned long long* msk=(unsigned long long*)carve(2ull*TOTK*32*8);
  double* part   =(double*)carve(256*2*8);
  unsigned long long* keepbuf=(unsigned long long*)carve(2*124*8);   // init in k_mid2
  if ((size_t)(p-(char*)d_ws) > ws_size) return;

  hipMemsetAsync(highest, 0, 1024, stream);  // highest + counts + flags (contiguous)

  uint32_t a0,b0,a1,b1;
  threefry(0u,42u,0u,2u,&a0,&b0);
  threefry(0u,42u,1u,3u,&a1,&b1);
  uint32_t kf00,kf01,kb00,kb01,kf10,kf11,kb10,kb11;
  { uint32_t c0,d0,c1,d1;
    threefry(a0,a1,0u,2u,&c0,&d0); threefry(a0,a1,1u,3u,&c1,&d1);
    kf00=c0; kf01=c1; kb00=d0; kb01=d1;
    threefry(b0,b1,0u,2u,&c0,&d0); threefry(b0,b1,1u,3u,&c1,&d1);
    kf10=c0; kf11=c1; kb10=d0; kb11=d1; }

  k_pre<<<704, 256, 0, stream>>>(cw, cwTf, gt, highest);
  k_conv_label<<<4775, 256, 0, stream>>>(feats[0],feats[1],feats[2],feats[3],feats[4],
      cwTf,cb,ow,ob,dwt,dbt, logits, dpred,
      gt, highest, prelab, matched, labels, counts,
      ub, kf00,kf01,kb00,kb01,kf10,kf11,kb10,kb11);
  k_mid2<<<78, 1024, 0, stream>>>(ub, prelab, counts, labels, logits, dpred,
      allS, allB, keepbuf, gt, matched, part, flags);
  k_mid3post<<<511, 1024, 0, stream>>>(allB, msk, part, allS, flags, keepbuf, out);
}